// Round 13
// baseline (327.536 us; speedup 1.0000x reference)
//
#include <hip/hip_runtime.h>

// GCN encoder: h1 = relu(x@fcW+fcb); h2 = relu(gcn(h1,W1,b1)); out = relu(gcn(h2,W2,b2))
// gcn(x,W,b)[i] = sum_{e:dst=i} (x@W)[src_e]*norm_e + (x@W)[i]*dinv[i]^2 + b
// Aggregation: dst-sorted CSR on device; per-node float4 gather.
// GEMM: split-bf16 MFMA (hi/lo planes, 3 passes) with NO LDS: each lane
// gathers its fragment directly from L2 (A[M][Kpad], BT[N][Kpad] layouts put
// a fragment at row*Kpad+kg*8; the wave's 4 kg-groups cover 64B contiguous
// per row -> 16 fully-used cache lines per wave-load). Round 12 analysis:
// LDS round-trip was ~437 cyc/block-K-step vs 58 cyc of MFMA, 2 barriers per
// K-step, nothing pipelined. No LDS -> no barriers -> compiler pipelines the
// pure load->mfma loop. A planes are K-padded with zeros (pad written by
// producers) so fragment k-tails are exact; M/N tails use clamped reads
// (garbage only lands in unwritten rows/cols).
// No min-waves in __launch_bounds__ (rounds 5/6: hipcc spills to meet it).

typedef unsigned short us;

namespace {
constexpr int NN = 20000;
constexpr int NE = 320000;
constexpr int IN_FT = 256, HID1 = 400, HID2 = 200, OUT_FT = 128;
constexpr int K1P = 416;  // HID1 padded to 32
constexpr int K2P = 224;  // HID2 padded to 32
using short8v = __attribute__((ext_vector_type(8))) short;
using f32x4 = __attribute__((ext_vector_type(4))) float;
}

__device__ __forceinline__ us f2bf(float f) {
  unsigned int u = __float_as_uint(f);
  u += 0x7FFFu + ((u >> 16) & 1u);  // round-to-nearest-even
  return (us)(u >> 16);
}
__device__ __forceinline__ float bf2f(us h) {
  return __uint_as_float(((unsigned int)h) << 16);
}

// deg (weighted, +1 self loop) and integer count per dst in one pass
__global__ __launch_bounds__(256) void deg_count_kernel(const int* __restrict__ dst,
                                                        const float* __restrict__ ew,
                                                        float* __restrict__ deg,
                                                        int* __restrict__ cnt) {
  int tid = blockIdx.x * 256 + threadIdx.x;
  if (tid < NE) {
    int d = dst[tid];
    unsafeAtomicAdd(&deg[d], ew[tid]);
    atomicAdd(&cnt[d], 1);
  } else if (tid < NE + NN) {
    unsafeAtomicAdd(&deg[tid - NE], 1.0f);  // self-loop weight 1
  }
}

// single block: deg -> dinv in place, exclusive scan count -> rowptr,
// count overwritten with exclusive prefix (scatter fill cursor).
__global__ __launch_bounds__(1024) void scan_dinv_kernel(int* __restrict__ count,
                                                         int* __restrict__ rowptr,
                                                         float* __restrict__ deg) {
  constexpr int CHUNK = (NN + 1023) / 1024;  // 20
  __shared__ int partial[1024];
  const int t = threadIdx.x;
  const int base = t * CHUNK;
#pragma unroll
  for (int i = 0; i < CHUNK; ++i) {  // dinv (independent of scan arrays)
    int idx = base + i;
    if (idx < NN) {
      float d = deg[idx];
      deg[idx] = d > 0.f ? rsqrtf(d) : 0.f;
    }
  }
  int s = 0;
#pragma unroll
  for (int i = 0; i < CHUNK; ++i) {
    int idx = base + i;
    if (idx < NN) s += count[idx];
  }
  partial[t] = s;
  __syncthreads();
  for (int off = 1; off < 1024; off <<= 1) {
    int v = 0;
    if (t >= off) v = partial[t - off];
    __syncthreads();
    if (t >= off) partial[t] += v;
    __syncthreads();
  }
  int excl = partial[t] - s;
#pragma unroll
  for (int i = 0; i < CHUNK; ++i) {
    int idx = base + i;
    if (idx < NN) {
      int c = count[idx];
      rowptr[idx] = excl;
      count[idx] = excl;  // scatter fill cursor
      excl += c;
    }
  }
  if (t == 1023) rowptr[NN] = partial[1023];
}

// scatter edges into dst-sorted order, computing norm inline
__global__ __launch_bounds__(256) void scatter_kernel(const int* __restrict__ src,
                                                      const int* __restrict__ dst,
                                                      const float* __restrict__ ew,
                                                      const float* __restrict__ dinv,
                                                      int* __restrict__ fill,
                                                      int* __restrict__ srcS,
                                                      float* __restrict__ wS) {
  int e = blockIdx.x * 256 + threadIdx.x;
  if (e >= NE) return;
  int s = src[e], d = dst[e];
  int pos = atomicAdd(&fill[d], 1);
  srcS[pos] = s;
  wS[pos] = dinv[s] * ew[e] * dinv[d];
}

// split fp32 array into bf16 hi/lo planes, 8 elems/thread (n % 8 == 0)
__global__ __launch_bounds__(256) void split_kernel(const float* __restrict__ in,
                                                    us* __restrict__ hi,
                                                    us* __restrict__ lo,
                                                    int n8) {
  int i = blockIdx.x * 256 + threadIdx.x;
  if (i >= n8) return;
  const float4 v0 = reinterpret_cast<const float4*>(in)[i * 2];
  const float4 v1 = reinterpret_cast<const float4*>(in)[i * 2 + 1];
  const float v[8] = {v0.x, v0.y, v0.z, v0.w, v1.x, v1.y, v1.z, v1.w};
  short8v h, l;
#pragma unroll
  for (int j = 0; j < 8; ++j) {
    us hh = f2bf(v[j]);
    h[j] = (short)hh;
    l[j] = (short)f2bf(v[j] - bf2f(hh));
  }
  reinterpret_cast<short8v*>(hi)[i] = h;
  reinterpret_cast<short8v*>(lo)[i] = l;
}

// all three weight transposes+splits in one kernel: W[K,N] -> [N][Kpad] hi/lo
__global__ __launch_bounds__(256) void wtrans_all_kernel(
    const float* __restrict__ fcW, const float* __restrict__ W1,
    const float* __restrict__ W2,
    us* __restrict__ fcWTh, us* __restrict__ fcWTl,
    us* __restrict__ W1Th, us* __restrict__ W1Tl,
    us* __restrict__ W2Th, us* __restrict__ W2Tl) {
  constexpr int N0 = HID1 * IN_FT;   // 102400
  constexpr int N1 = HID2 * K1P;     // 83200
  constexpr int N2 = OUT_FT * K2P;   // 28672
  int idx = blockIdx.x * 256 + threadIdx.x;
  float v;
  us *th, *tl;
  int o;
  if (idx < N0) {
    o = idx;
    int n = o / IN_FT, k = o - n * IN_FT;  // Kpad == K == 256
    v = fcW[(size_t)k * HID1 + n];
    th = fcWTh; tl = fcWTl;
  } else if (idx < N0 + N1) {
    o = idx - N0;
    int n = o / K1P, k = o - n * K1P;
    v = (k < HID1) ? W1[(size_t)k * HID2 + n] : 0.f;
    th = W1Th; tl = W1Tl;
  } else if (idx < N0 + N1 + N2) {
    o = idx - N0 - N1;
    int n = o / K2P, k = o - n * K2P;
    v = (k < HID2) ? W2[(size_t)k * OUT_FT + n] : 0.f;
    th = W2Th; tl = W2Tl;
  } else {
    return;
  }
  us h = f2bf(v);
  th[o] = h;
  tl[o] = f2bf(v - bf2f(h));
}

// C[M,N] = A[M,KAP] @ BT[N,KAP]^T from pre-split zero-K-padded planes.
// NO LDS, NO barriers: lanes gather fragments straight from L2.
// 64x64 block tile; 4 waves, each 32x32 (2x2 16x16 frags); 3 mfma passes.
// SPLIT: write Ch/Cl planes with row stride NPAD, zero-filling cols [N,NPAD).
template <int KAP, bool BIAS, bool RELU, bool SPLIT>
__global__ __launch_bounds__(256) void gemm_direct_kernel(
    const us* __restrict__ Ah, const us* __restrict__ Al,
    const us* __restrict__ BTh, const us* __restrict__ BTl,
    const float* __restrict__ bias, float* __restrict__ Cf,
    us* __restrict__ Ch, us* __restrict__ Cl,
    int M, int N, int NPAD) {
  const int tid = threadIdx.x;
  const int lane = tid & 63;
  const int wid = tid >> 6;
  const int wm = wid >> 1, wn = wid & 1;  // 2x2 wave grid
  const int m0 = blockIdx.y * 64, n0 = blockIdx.x * 64;
  const int l15 = lane & 15, kg = lane >> 4;

  // per-lane fragment base pointers (row/col clamped: garbage only reaches
  // out rows >= M / cols >= N, which are never written)
  const us* abase[2][2];  // [mf][hi/lo]
  const us* bbase[2][2];  // [nf][hi/lo]
#pragma unroll
  for (int mf = 0; mf < 2; ++mf) {
    int r = m0 + wm * 32 + mf * 16 + l15;
    if (r > M - 1) r = M - 1;
    size_t o = (size_t)r * KAP + kg * 8;
    abase[mf][0] = Ah + o;
    abase[mf][1] = Al + o;
  }
#pragma unroll
  for (int nf = 0; nf < 2; ++nf) {
    int c = n0 + wn * 32 + nf * 16 + l15;
    if (c > N - 1) c = N - 1;
    size_t o = (size_t)c * KAP + kg * 8;
    bbase[nf][0] = BTh + o;
    bbase[nf][1] = BTl + o;
  }

  f32x4 acc[2][2];
#pragma unroll
  for (int i = 0; i < 2; ++i)
#pragma unroll
    for (int j = 0; j < 2; ++j)
#pragma unroll
      for (int c = 0; c < 4; ++c) acc[i][j][c] = 0.f;

#pragma unroll 2
  for (int k0 = 0; k0 < KAP; k0 += 32) {
    short8v afh[2], afl[2], bfh[2], bfl[2];
#pragma unroll
    for (int mf = 0; mf < 2; ++mf) {
      afh[mf] = *reinterpret_cast<const short8v*>(abase[mf][0] + k0);
      afl[mf] = *reinterpret_cast<const short8v*>(abase[mf][1] + k0);
    }
#pragma unroll
    for (int nf = 0; nf < 2; ++nf) {
      bfh[nf] = *reinterpret_cast<const short8v*>(bbase[nf][0] + k0);
      bfl[nf] = *reinterpret_cast<const short8v*>(bbase[nf][1] + k0);
    }
#pragma unroll
    for (int mf = 0; mf < 2; ++mf)
#pragma unroll
      for (int nf = 0; nf < 2; ++nf) {
        acc[mf][nf] = __builtin_amdgcn_mfma_f32_16x16x32_bf16(afh[mf], bfh[nf], acc[mf][nf], 0, 0, 0);
        acc[mf][nf] = __builtin_amdgcn_mfma_f32_16x16x32_bf16(afh[mf], bfl[nf], acc[mf][nf], 0, 0, 0);
        acc[mf][nf] = __builtin_amdgcn_mfma_f32_16x16x32_bf16(afl[mf], bfh[nf], acc[mf][nf], 0, 0, 0);
      }
  }

  // epilogue: C/D layout col=lane&15, row=(lane>>4)*4+reg (guide §3, m89/m91)
#pragma unroll
  for (int nf = 0; nf < 2; ++nf) {
    const int col = n0 + wn * 32 + nf * 16 + l15;
    float bb = 0.f;
    if (BIAS && col < N) bb = bias[col];
#pragma unroll
    for (int mf = 0; mf < 2; ++mf) {
      const int rbase = m0 + wm * 32 + mf * 16 + kg * 4;
#pragma unroll
      for (int i = 0; i < 4; ++i) {
        const int row = rbase + i;
        if (row >= M) continue;
        if (col < N) {
          float v = acc[mf][nf][i];
          if (BIAS) v += bb;
          if (RELU) v = fmaxf(v, 0.f);
          if (SPLIT) {
            us h = f2bf(v);
            Ch[(size_t)row * NPAD + col] = h;
            Cl[(size_t)row * NPAD + col] = f2bf(v - bf2f(h));
          } else {
            Cf[(size_t)row * N + col] = v;
          }
        } else if (SPLIT && col < NPAD) {  // zero the K-pad for the next GEMM
          Ch[(size_t)row * NPAD + col] = 0;
          Cl[(size_t)row * NPAD + col] = 0;
        }
      }
    }
  }
}

// Fused gather-aggregate + self-loop + bias + relu.
// NPW nodes/wave; F/4 lanes per node, ONE float4 per edge per lane.
// SPLIT: write bf16 hi/lo planes with row stride OST, zero-pad cols [F,OST).
template <int F, int OST, int NPW, bool SPLIT>
__global__ __launch_bounds__(256) void agg_gather_kernel(const int* __restrict__ rowptr,
                                                         const int* __restrict__ srcS,
                                                         const float* __restrict__ wS,
                                                         const float* __restrict__ t,
                                                         const float* __restrict__ dinv,
                                                         const float* __restrict__ bias,
                                                         float* __restrict__ out,
                                                         us* __restrict__ oh,
                                                         us* __restrict__ ol) {
  constexpr int LPN = F / 4;    // float4 lanes per node
  constexpr int LPNP = OST / 4; // lanes incl. pad
  const int wv = threadIdx.x >> 6;
  const int lane = threadIdx.x & 63;
  const int sub = (NPW == 2) ? (lane >> 5) : 0;
  const int l = (NPW == 2) ? (lane & 31) : lane;
  const int node = blockIdx.x * (4 * NPW) + wv * NPW + sub;
  if (node >= NN) return;
  if (l >= LPN) {
    if (SPLIT && l < LPNP) {  // zero the K-pad for the next GEMM
      ushort4 z = make_ushort4(0, 0, 0, 0);
      *reinterpret_cast<ushort4*>(oh + (size_t)node * OST + l * 4) = z;
      *reinterpret_cast<ushort4*>(ol + (size_t)node * OST + l * 4) = z;
    }
    return;  // no barriers/shuffles below: safe exit
  }
  const int beg = rowptr[node], end = rowptr[node + 1];
  const size_t fo = (size_t)l * 4;
  float4 acc0 = make_float4(0.f, 0.f, 0.f, 0.f);
  float4 acc1 = make_float4(0.f, 0.f, 0.f, 0.f);
  int j = beg;
  for (; j + 1 < end; j += 2) {  // 2-way unroll: independent load->FMA chains
    const int s0 = srcS[j], s1 = srcS[j + 1];
    const float w0 = wS[j], w1 = wS[j + 1];
    const float4 v0 = *reinterpret_cast<const float4*>(t + (size_t)s0 * F + fo);
    const float4 v1 = *reinterpret_cast<const float4*>(t + (size_t)s1 * F + fo);
    acc0.x = fmaf(v0.x, w0, acc0.x); acc0.y = fmaf(v0.y, w0, acc0.y);
    acc0.z = fmaf(v0.z, w0, acc0.z); acc0.w = fmaf(v0.w, w0, acc0.w);
    acc1.x = fmaf(v1.x, w1, acc1.x); acc1.y = fmaf(v1.y, w1, acc1.y);
    acc1.z = fmaf(v1.z, w1, acc1.z); acc1.w = fmaf(v1.w, w1, acc1.w);
  }
  if (j < end) {
    const int s0 = srcS[j];
    const float w0 = wS[j];
    const float4 v0 = *reinterpret_cast<const float4*>(t + (size_t)s0 * F + fo);
    acc0.x = fmaf(v0.x, w0, acc0.x); acc0.y = fmaf(v0.y, w0, acc0.y);
    acc0.z = fmaf(v0.z, w0, acc0.z); acc0.w = fmaf(v0.w, w0, acc0.w);
  }
  const float di = dinv[node];
  const float sw = di * di;
  const float4 tv = *reinterpret_cast<const float4*>(t + (size_t)node * F + fo);
  const float4 bb = *reinterpret_cast<const float4*>(bias + fo);
  float4 o;
  o.x = fmaxf(fmaf(tv.x, sw, acc0.x + acc1.x) + bb.x, 0.f);
  o.y = fmaxf(fmaf(tv.y, sw, acc0.y + acc1.y) + bb.y, 0.f);
  o.z = fmaxf(fmaf(tv.z, sw, acc0.z + acc1.z) + bb.z, 0.f);
  o.w = fmaxf(fmaf(tv.w, sw, acc0.w + acc1.w) + bb.w, 0.f);
  if (SPLIT) {
    ushort4 hv, lv;
    hv.x = f2bf(o.x); lv.x = f2bf(o.x - bf2f(hv.x));
    hv.y = f2bf(o.y); lv.y = f2bf(o.y - bf2f(hv.y));
    hv.z = f2bf(o.z); lv.z = f2bf(o.z - bf2f(hv.z));
    hv.w = f2bf(o.w); lv.w = f2bf(o.w - bf2f(hv.w));
    *reinterpret_cast<ushort4*>(oh + (size_t)node * OST + fo) = hv;
    *reinterpret_cast<ushort4*>(ol + (size_t)node * OST + fo) = lv;
  } else {
    *reinterpret_cast<float4*>(out + (size_t)node * F + fo) = o;
  }
}

extern "C" void kernel_launch(void* const* d_in, const int* in_sizes, int n_in,
                              void* d_out, int out_size, void* d_ws, size_t ws_size,
                              hipStream_t stream) {
  const float* x = (const float*)d_in[0];
  const int* ei = (const int*)d_in[1];  // int32 per harness conversion
  const float* ea = (const float*)d_in[2];
  const float* fcW = (const float*)d_in[3];
  const float* fcb = (const float*)d_in[4];
  const float* W1 = (const float*)d_in[5];
  const float* b1 = (const float*)d_in[6];
  const float* W2 = (const float*)d_in[7];
  const float* b2 = (const float*)d_in[8];
  const int* srcIdx = ei;       // edge_index[0]
  const int* dstIdx = ei + NE;  // edge_index[1]

  char* ws = (char*)d_ws;
  constexpr size_t KB_ = 1u << 10;
  float* dinv = (float*)(ws);                    // 80000 B (doubles as deg)
  int* cnt = (int*)(ws + 80000);                 // 80000 B (count -> cursor)
  int* rowptr = (int*)(ws + 160000);             // 80004 B
  int* srcS = (int*)(ws + 256 * KB_);            // 1.28 MB
  float* wS = (float*)(ws + 1536 * KB_);         // 1.28 MB
  us* fcWTh = (us*)(ws + 2880 * KB_);            // 204800 B
  us* fcWTl = (us*)(ws + 3088 * KB_);
  us* W1Th = (us*)(ws + 3296 * KB_);             // 166400 B
  us* W1Tl = (us*)(ws + 3464 * KB_);
  us* W2Th = (us*)(ws + 3632 * KB_);             // 57344 B
  us* W2Tl = (us*)(ws + 3696 * KB_);
  us* xh = (us*)(ws + 3776 * KB_);               // 10.24 MB
  us* xl = (us*)(ws + 13784 * KB_);              // 10.24 MB, ends ~23.3 MB
  us* h1h = (us*)(ws + 23800 * KB_);             // 20000x416x2B = 16.64 MB
  us* h1l = (us*)(ws + 40060 * KB_);             // ends ~55.3 MB (peak)
  float* t1 = (float*)(ws + 3776 * KB_);         // 16 MB (x dead); also t2
  us* h2h = (us*)(ws + 23800 * KB_);             // 8.96 MB (h1 dead)
  us* h2l = (us*)(ws + 32600 * KB_);
  float* t2 = (float*)(ws + 3776 * KB_);         // 10.24 MB (t1 dead)

  // --- normalization + CSR (shared by both GCN layers) ---
  hipMemsetAsync(dinv, 0, 160000, stream);  // dinv + cnt contiguous
  deg_count_kernel<<<(NE + NN + 255) / 256, 256, 0, stream>>>(dstIdx, ea, dinv, cnt);
  scan_dinv_kernel<<<1, 1024, 0, stream>>>(cnt, rowptr, dinv);
  scatter_kernel<<<(NE + 255) / 256, 256, 0, stream>>>(srcIdx, dstIdx, ea, dinv, cnt, srcS, wS);

  // --- one-time operand prep: split x, transpose+split all weights ---
  split_kernel<<<(NN * IN_FT / 8 + 255) / 256, 256, 0, stream>>>(x, xh, xl, NN * IN_FT / 8);
  {
    constexpr int WT = HID1 * IN_FT + HID2 * K1P + OUT_FT * K2P;
    wtrans_all_kernel<<<(WT + 255) / 256, 256, 0, stream>>>(
        fcW, W1, W2, fcWTh, fcWTl, W1Th, W1Tl, W2Th, W2Tl);
  }

  const int MBLK = (NN + 63) / 64;  // 313 row blocks

  // --- h1 = relu(x @ fcW + fcb), written as bf16 hi/lo planes [NN][416] ---
  gemm_direct_kernel<IN_FT, true, true, true><<<dim3((HID1 + 63) / 64, MBLK), 256, 0, stream>>>(
      xh, xl, fcWTh, fcWTl, fcb, nullptr, h1h, h1l, NN, HID1, K1P);

  // --- layer 1: t1 = h1 @ W1 (fp32); h2 = relu(agg(t1)+..) planes [NN][224] ---
  gemm_direct_kernel<K1P, false, false, false><<<dim3((HID2 + 63) / 64, MBLK), 256, 0, stream>>>(
      h1h, h1l, W1Th, W1Tl, nullptr, t1, nullptr, nullptr, NN, HID2, HID2);
  agg_gather_kernel<HID2, K2P, 1, true><<<(NN + 3) / 4, 256, 0, stream>>>(
      rowptr, srcS, wS, t1, dinv, b1, nullptr, h2h, h2l);

  // --- layer 2: t2 = h2 @ W2 (fp32); out = relu(agg(t2)+..) fp32 ---
  gemm_direct_kernel<K2P, false, false, false><<<dim3((OUT_FT + 63) / 64, MBLK), 256, 0, stream>>>(
      h2h, h2l, W2Th, W2Tl, nullptr, t2, nullptr, nullptr, NN, OUT_FT, OUT_FT);
  agg_gather_kernel<OUT_FT, OUT_FT, 2, false><<<(NN + 7) / 8, 256, 0, stream>>>(
      rowptr, srcS, wS, t2, dinv, b2, (float*)d_out, nullptr, nullptr);
}

// Round 14
// 287.446 us; speedup vs baseline: 1.1395x; 1.1395x over previous
//
#include <hip/hip_runtime.h>

// GCN encoder: h1 = relu(x@fcW+fcb); h2 = relu(gcn(h1,W1,b1)); out = relu(gcn(h2,W2,b2))
// gcn(x,W,b)[i] = sum_{e:dst=i} (x@W)[src_e]*norm_e + (x@W)[i]*dinv[i]^2 + b
// Aggregation: dst-sorted CSR on device; per-node float4 gather.
// GEMM (A-resident): M-tile 32 (NN/32=625 blocks, no row tail). Both A hi/lo
// planes staged to LDS ONCE per block (stride KAP+4 -> 2-way-free frag
// reads); then a BARRIER-FREE n*k loop: 4 LDS b128 (A frags) + 2 global b128
// (B frags, [n][k] layout) + 6 mfma per K-step per wave (wave = 2 m-frags x
// 1 n-frag; 4 waves cover 64 cols/n-iter). A read from HBM once per GEMM
// (round 12: re-read per column block, 2.5x HBM floor); B (<=420 KB) is
// L2-resident per XCD. Round 13 (all-direct, no reuse) and round 12
// (2-barrier LDS K-step) both analyzed in comments history.
// No min-waves in __launch_bounds__ (rounds 5/6: hipcc spills to meet it).

typedef unsigned short us;

namespace {
constexpr int NN = 20000;
constexpr int NE = 320000;
constexpr int IN_FT = 256, HID1 = 400, HID2 = 200, OUT_FT = 128;
constexpr int K1P = 416;  // HID1 padded to 32
constexpr int K2P = 224;  // HID2 padded to 32
using short8v = __attribute__((ext_vector_type(8))) short;
using f32x4 = __attribute__((ext_vector_type(4))) float;
}

__device__ __forceinline__ us f2bf(float f) {
  unsigned int u = __float_as_uint(f);
  u += 0x7FFFu + ((u >> 16) & 1u);  // round-to-nearest-even
  return (us)(u >> 16);
}
__device__ __forceinline__ float bf2f(us h) {
  return __uint_as_float(((unsigned int)h) << 16);
}

// deg (weighted, +1 self loop) and integer count per dst in one pass
__global__ __launch_bounds__(256) void deg_count_kernel(const int* __restrict__ dst,
                                                        const float* __restrict__ ew,
                                                        float* __restrict__ deg,
                                                        int* __restrict__ cnt) {
  int tid = blockIdx.x * 256 + threadIdx.x;
  if (tid < NE) {
    int d = dst[tid];
    unsafeAtomicAdd(&deg[d], ew[tid]);
    atomicAdd(&cnt[d], 1);
  } else if (tid < NE + NN) {
    unsafeAtomicAdd(&deg[tid - NE], 1.0f);  // self-loop weight 1
  }
}

// single block: deg -> dinv in place, exclusive scan count -> rowptr,
// count overwritten with exclusive prefix (scatter fill cursor).
__global__ __launch_bounds__(1024) void scan_dinv_kernel(int* __restrict__ count,
                                                         int* __restrict__ rowptr,
                                                         float* __restrict__ deg) {
  constexpr int CHUNK = (NN + 1023) / 1024;  // 20
  __shared__ int partial[1024];
  const int t = threadIdx.x;
  const int base = t * CHUNK;
#pragma unroll
  for (int i = 0; i < CHUNK; ++i) {  // dinv (independent of scan arrays)
    int idx = base + i;
    if (idx < NN) {
      float d = deg[idx];
      deg[idx] = d > 0.f ? rsqrtf(d) : 0.f;
    }
  }
  int s = 0;
#pragma unroll
  for (int i = 0; i < CHUNK; ++i) {
    int idx = base + i;
    if (idx < NN) s += count[idx];
  }
  partial[t] = s;
  __syncthreads();
  for (int off = 1; off < 1024; off <<= 1) {
    int v = 0;
    if (t >= off) v = partial[t - off];
    __syncthreads();
    if (t >= off) partial[t] += v;
    __syncthreads();
  }
  int excl = partial[t] - s;
#pragma unroll
  for (int i = 0; i < CHUNK; ++i) {
    int idx = base + i;
    if (idx < NN) {
      int c = count[idx];
      rowptr[idx] = excl;
      count[idx] = excl;  // scatter fill cursor
      excl += c;
    }
  }
  if (t == 1023) rowptr[NN] = partial[1023];
}

// scatter edges into dst-sorted order, computing norm inline
__global__ __launch_bounds__(256) void scatter_kernel(const int* __restrict__ src,
                                                      const int* __restrict__ dst,
                                                      const float* __restrict__ ew,
                                                      const float* __restrict__ dinv,
                                                      int* __restrict__ fill,
                                                      int* __restrict__ srcS,
                                                      float* __restrict__ wS) {
  int e = blockIdx.x * 256 + threadIdx.x;
  if (e >= NE) return;
  int s = src[e], d = dst[e];
  int pos = atomicAdd(&fill[d], 1);
  srcS[pos] = s;
  wS[pos] = dinv[s] * ew[e] * dinv[d];
}

// split fp32 array into bf16 hi/lo planes, 8 elems/thread (n % 8 == 0)
__global__ __launch_bounds__(256) void split_kernel(const float* __restrict__ in,
                                                    us* __restrict__ hi,
                                                    us* __restrict__ lo,
                                                    int n8) {
  int i = blockIdx.x * 256 + threadIdx.x;
  if (i >= n8) return;
  const float4 v0 = reinterpret_cast<const float4*>(in)[i * 2];
  const float4 v1 = reinterpret_cast<const float4*>(in)[i * 2 + 1];
  const float v[8] = {v0.x, v0.y, v0.z, v0.w, v1.x, v1.y, v1.z, v1.w};
  short8v h, l;
#pragma unroll
  for (int j = 0; j < 8; ++j) {
    us hh = f2bf(v[j]);
    h[j] = (short)hh;
    l[j] = (short)f2bf(v[j] - bf2f(hh));
  }
  reinterpret_cast<short8v*>(hi)[i] = h;
  reinterpret_cast<short8v*>(lo)[i] = l;
}

// all three weight transposes+splits in one kernel: W[K,N] -> [N][Kpad] hi/lo
__global__ __launch_bounds__(256) void wtrans_all_kernel(
    const float* __restrict__ fcW, const float* __restrict__ W1,
    const float* __restrict__ W2,
    us* __restrict__ fcWTh, us* __restrict__ fcWTl,
    us* __restrict__ W1Th, us* __restrict__ W1Tl,
    us* __restrict__ W2Th, us* __restrict__ W2Tl) {
  constexpr int N0 = HID1 * IN_FT;   // 102400
  constexpr int N1 = HID2 * K1P;     // 83200
  constexpr int N2 = OUT_FT * K2P;   // 28672
  int idx = blockIdx.x * 256 + threadIdx.x;
  float v;
  us *th, *tl;
  int o;
  if (idx < N0) {
    o = idx;
    int n = o / IN_FT, k = o - n * IN_FT;  // Kpad == K == 256
    v = fcW[(size_t)k * HID1 + n];
    th = fcWTh; tl = fcWTl;
  } else if (idx < N0 + N1) {
    o = idx - N0;
    int n = o / K1P, k = o - n * K1P;
    v = (k < HID1) ? W1[(size_t)k * HID2 + n] : 0.f;
    th = W1Th; tl = W1Tl;
  } else if (idx < N0 + N1 + N2) {
    o = idx - N0 - N1;
    int n = o / K2P, k = o - n * K2P;
    v = (k < HID2) ? W2[(size_t)k * OUT_FT + n] : 0.f;
    th = W2Th; tl = W2Tl;
  } else {
    return;
  }
  us h = f2bf(v);
  th[o] = h;
  tl[o] = f2bf(v - bf2f(h));
}

// C[NN,N] = A[NN,KAP] @ BT[N,KAP]^T, split-bf16 (3 mfma passes).
// A-resident: block = 32 rows; A hi/lo staged to LDS once (stride KAP+4);
// barrier-free n*k loop, B frags direct from L2. Wave w = n-frag w;
// each wave: 2 m-frags x 1 n-frag; block covers 64 cols per n-iter.
// SPLIT: write Ch/Cl planes (row stride NPAD, zero-fill cols [N,NPAD)).
template <int KAP, bool BIAS, bool RELU, bool SPLIT>
__global__ __launch_bounds__(256) void gemm_ares_kernel(
    const us* __restrict__ Ah, const us* __restrict__ Al,
    const us* __restrict__ BTh, const us* __restrict__ BTl,
    const float* __restrict__ bias, float* __restrict__ Cf,
    us* __restrict__ Ch, us* __restrict__ Cl,
    int N, int NPAD) {
  constexpr int MT = 32;
  constexpr int LDK = KAP + 4;  // pad: frag-read banks 2-way max (free)
  __shared__ us Ash[MT][LDK];
  __shared__ us Asl[MT][LDK];
  const int tid = threadIdx.x;
  const int lane = tid & 63;
  const int w = tid >> 6;            // wave id = n-frag selector
  const int l15 = lane & 15, kg = lane >> 4;
  const int m0 = blockIdx.x * MT;    // NN % 32 == 0: no row tail

  {  // stage A rows m0..m0+31, both planes (coalesced b128)
    constexpr int CH = MT * KAP / 8;
    for (int i = tid; i < CH; i += 256) {
      const int r = i / (KAP / 8);
      const int c = (i - r * (KAP / 8)) * 8;
      const size_t go = (size_t)(m0 + r) * KAP + c;
      *reinterpret_cast<short8v*>(&Ash[r][c]) = *reinterpret_cast<const short8v*>(Ah + go);
      *reinterpret_cast<short8v*>(&Asl[r][c]) = *reinterpret_cast<const short8v*>(Al + go);
    }
  }
  __syncthreads();  // the only barrier in the kernel

  for (int n0 = 0; n0 < N; n0 += 64) {
    const int col = n0 + w * 16 + l15;
    const int cc = col < N ? col : N - 1;  // clamped read; epilogue skips col>=N
    const us* bh = BTh + (size_t)cc * KAP + kg * 8;
    const us* bl = BTl + (size_t)cc * KAP + kg * 8;
    f32x4 acc0 = {0.f, 0.f, 0.f, 0.f};
    f32x4 acc1 = {0.f, 0.f, 0.f, 0.f};
    for (int k0 = 0; k0 < KAP; k0 += 32) {
      const int ka = k0 + kg * 8;
      short8v a0h = *reinterpret_cast<const short8v*>(&Ash[l15][ka]);
      short8v a0l = *reinterpret_cast<const short8v*>(&Asl[l15][ka]);
      short8v a1h = *reinterpret_cast<const short8v*>(&Ash[16 + l15][ka]);
      short8v a1l = *reinterpret_cast<const short8v*>(&Asl[16 + l15][ka]);
      short8v vbh = *reinterpret_cast<const short8v*>(bh + k0);
      short8v vbl = *reinterpret_cast<const short8v*>(bl + k0);
      acc0 = __builtin_amdgcn_mfma_f32_16x16x32_bf16(a0h, vbh, acc0, 0, 0, 0);
      acc1 = __builtin_amdgcn_mfma_f32_16x16x32_bf16(a1h, vbh, acc1, 0, 0, 0);
      acc0 = __builtin_amdgcn_mfma_f32_16x16x32_bf16(a0h, vbl, acc0, 0, 0, 0);
      acc1 = __builtin_amdgcn_mfma_f32_16x16x32_bf16(a1h, vbl, acc1, 0, 0, 0);
      acc0 = __builtin_amdgcn_mfma_f32_16x16x32_bf16(a0l, vbh, acc0, 0, 0, 0);
      acc1 = __builtin_amdgcn_mfma_f32_16x16x32_bf16(a1l, vbh, acc1, 0, 0, 0);
    }
    // epilogue: C/D layout col=lane&15, row=(lane>>4)*4+reg (guide §3, m89/m91)
    if (col < N) {
      float bb = 0.f;
      if (BIAS) bb = bias[col];
#pragma unroll
      for (int mf = 0; mf < 2; ++mf) {
        const f32x4& a = mf ? acc1 : acc0;
        const int rbase = m0 + mf * 16 + kg * 4;
#pragma unroll
        for (int i = 0; i < 4; ++i) {
          float v = a[i];
          if (BIAS) v += bb;
          if (RELU) v = fmaxf(v, 0.f);
          if (SPLIT) {
            us h = f2bf(v);
            Ch[(size_t)(rbase + i) * NPAD + col] = h;
            Cl[(size_t)(rbase + i) * NPAD + col] = f2bf(v - bf2f(h));
          } else {
            Cf[(size_t)(rbase + i) * N + col] = v;
          }
        }
      }
    } else if (SPLIT && col < NPAD) {  // zero the K-pad for the next GEMM
#pragma unroll
      for (int mf = 0; mf < 2; ++mf) {
        const int rbase = m0 + mf * 16 + kg * 4;
#pragma unroll
        for (int i = 0; i < 4; ++i) {
          Ch[(size_t)(rbase + i) * NPAD + col] = 0;
          Cl[(size_t)(rbase + i) * NPAD + col] = 0;
        }
      }
    }
  }
}

// Fused gather-aggregate + self-loop + bias + relu.
// NPW nodes/wave; F/4 lanes per node, ONE float4 per edge per lane.
// SPLIT: write bf16 hi/lo planes with row stride OST, zero-pad cols [F,OST).
template <int F, int OST, int NPW, bool SPLIT>
__global__ __launch_bounds__(256) void agg_gather_kernel(const int* __restrict__ rowptr,
                                                         const int* __restrict__ srcS,
                                                         const float* __restrict__ wS,
                                                         const float* __restrict__ t,
                                                         const float* __restrict__ dinv,
                                                         const float* __restrict__ bias,
                                                         float* __restrict__ out,
                                                         us* __restrict__ oh,
                                                         us* __restrict__ ol) {
  constexpr int LPN = F / 4;    // float4 lanes per node
  constexpr int LPNP = OST / 4; // lanes incl. pad
  const int wv = threadIdx.x >> 6;
  const int lane = threadIdx.x & 63;
  const int sub = (NPW == 2) ? (lane >> 5) : 0;
  const int l = (NPW == 2) ? (lane & 31) : lane;
  const int node = blockIdx.x * (4 * NPW) + wv * NPW + sub;
  if (node >= NN) return;
  if (l >= LPN) {
    if (SPLIT && l < LPNP) {  // zero the K-pad for the next GEMM
      ushort4 z = make_ushort4(0, 0, 0, 0);
      *reinterpret_cast<ushort4*>(oh + (size_t)node * OST + l * 4) = z;
      *reinterpret_cast<ushort4*>(ol + (size_t)node * OST + l * 4) = z;
    }
    return;  // no barriers/shuffles below: safe exit
  }
  const int beg = rowptr[node], end = rowptr[node + 1];
  const size_t fo = (size_t)l * 4;
  float4 acc0 = make_float4(0.f, 0.f, 0.f, 0.f);
  float4 acc1 = make_float4(0.f, 0.f, 0.f, 0.f);
  int j = beg;
  for (; j + 1 < end; j += 2) {  // 2-way unroll: independent load->FMA chains
    const int s0 = srcS[j], s1 = srcS[j + 1];
    const float w0 = wS[j], w1 = wS[j + 1];
    const float4 v0 = *reinterpret_cast<const float4*>(t + (size_t)s0 * F + fo);
    const float4 v1 = *reinterpret_cast<const float4*>(t + (size_t)s1 * F + fo);
    acc0.x = fmaf(v0.x, w0, acc0.x); acc0.y = fmaf(v0.y, w0, acc0.y);
    acc0.z = fmaf(v0.z, w0, acc0.z); acc0.w = fmaf(v0.w, w0, acc0.w);
    acc1.x = fmaf(v1.x, w1, acc1.x); acc1.y = fmaf(v1.y, w1, acc1.y);
    acc1.z = fmaf(v1.z, w1, acc1.z); acc1.w = fmaf(v1.w, w1, acc1.w);
  }
  if (j < end) {
    const int s0 = srcS[j];
    const float w0 = wS[j];
    const float4 v0 = *reinterpret_cast<const float4*>(t + (size_t)s0 * F + fo);
    acc0.x = fmaf(v0.x, w0, acc0.x); acc0.y = fmaf(v0.y, w0, acc0.y);
    acc0.z = fmaf(v0.z, w0, acc0.z); acc0.w = fmaf(v0.w, w0, acc0.w);
  }
  const float di = dinv[node];
  const float sw = di * di;
  const float4 tv = *reinterpret_cast<const float4*>(t + (size_t)node * F + fo);
  const float4 bb = *reinterpret_cast<const float4*>(bias + fo);
  float4 o;
  o.x = fmaxf(fmaf(tv.x, sw, acc0.x + acc1.x) + bb.x, 0.f);
  o.y = fmaxf(fmaf(tv.y, sw, acc0.y + acc1.y) + bb.y, 0.f);
  o.z = fmaxf(fmaf(tv.z, sw, acc0.z + acc1.z) + bb.z, 0.f);
  o.w = fmaxf(fmaf(tv.w, sw, acc0.w + acc1.w) + bb.w, 0.f);
  if (SPLIT) {
    ushort4 hv, lv;
    hv.x = f2bf(o.x); lv.x = f2bf(o.x - bf2f(hv.x));
    hv.y = f2bf(o.y); lv.y = f2bf(o.y - bf2f(hv.y));
    hv.z = f2bf(o.z); lv.z = f2bf(o.z - bf2f(hv.z));
    hv.w = f2bf(o.w); lv.w = f2bf(o.w - bf2f(hv.w));
    *reinterpret_cast<ushort4*>(oh + (size_t)node * OST + fo) = hv;
    *reinterpret_cast<ushort4*>(ol + (size_t)node * OST + fo) = lv;
  } else {
    *reinterpret_cast<float4*>(out + (size_t)node * F + fo) = o;
  }
}

extern "C" void kernel_launch(void* const* d_in, const int* in_sizes, int n_in,
                              void* d_out, int out_size, void* d_ws, size_t ws_size,
                              hipStream_t stream) {
  const float* x = (const float*)d_in[0];
  const int* ei = (const int*)d_in[1];  // int32 per harness conversion
  const float* ea = (const float*)d_in[2];
  const float* fcW = (const float*)d_in[3];
  const float* fcb = (const float*)d_in[4];
  const float* W1 = (const float*)d_in[5];
  const float* b1 = (const float*)d_in[6];
  const float* W2 = (const float*)d_in[7];
  const float* b2 = (const float*)d_in[8];
  const int* srcIdx = ei;       // edge_index[0]
  const int* dstIdx = ei + NE;  // edge_index[1]

  char* ws = (char*)d_ws;
  constexpr size_t KB_ = 1u << 10;
  float* dinv = (float*)(ws);                    // 80000 B (doubles as deg)
  int* cnt = (int*)(ws + 80000);                 // 80000 B (count -> cursor)
  int* rowptr = (int*)(ws + 160000);             // 80004 B
  int* srcS = (int*)(ws + 256 * KB_);            // 1.28 MB
  float* wS = (float*)(ws + 1536 * KB_);         // 1.28 MB
  us* fcWTh = (us*)(ws + 2880 * KB_);            // 204800 B
  us* fcWTl = (us*)(ws + 3088 * KB_);
  us* W1Th = (us*)(ws + 3296 * KB_);             // 166400 B
  us* W1Tl = (us*)(ws + 3464 * KB_);
  us* W2Th = (us*)(ws + 3632 * KB_);             // 57344 B
  us* W2Tl = (us*)(ws + 3696 * KB_);
  us* xh = (us*)(ws + 3776 * KB_);               // 10.24 MB
  us* xl = (us*)(ws + 13784 * KB_);              // 10.24 MB, ends ~23.3 MB
  us* h1h = (us*)(ws + 23800 * KB_);             // 20000x416x2B = 16.64 MB
  us* h1l = (us*)(ws + 40060 * KB_);             // ends ~55.3 MB (peak)
  float* t1 = (float*)(ws + 3776 * KB_);         // 16 MB (x dead); also t2
  us* h2h = (us*)(ws + 23800 * KB_);             // 8.96 MB (h1 dead)
  us* h2l = (us*)(ws + 32600 * KB_);
  float* t2 = (float*)(ws + 3776 * KB_);         // 10.24 MB (t1 dead)

  // --- normalization + CSR (shared by both GCN layers) ---
  hipMemsetAsync(dinv, 0, 160000, stream);  // dinv + cnt contiguous
  deg_count_kernel<<<(NE + NN + 255) / 256, 256, 0, stream>>>(dstIdx, ea, dinv, cnt);
  scan_dinv_kernel<<<1, 1024, 0, stream>>>(cnt, rowptr, dinv);
  scatter_kernel<<<(NE + 255) / 256, 256, 0, stream>>>(srcIdx, dstIdx, ea, dinv, cnt, srcS, wS);

  // --- one-time operand prep: split x, transpose+split all weights ---
  split_kernel<<<(NN * IN_FT / 8 + 255) / 256, 256, 0, stream>>>(x, xh, xl, NN * IN_FT / 8);
  {
    constexpr int WT = HID1 * IN_FT + HID2 * K1P + OUT_FT * K2P;
    wtrans_all_kernel<<<(WT + 255) / 256, 256, 0, stream>>>(
        fcW, W1, W2, fcWTh, fcWTl, W1Th, W1Tl, W2Th, W2Tl);
  }

  const int MBLK = NN / 32;  // 625 blocks, exact

  // --- h1 = relu(x @ fcW + fcb), written as bf16 hi/lo planes [NN][416] ---
  gemm_ares_kernel<IN_FT, true, true, true><<<MBLK, 256, 0, stream>>>(
      xh, xl, fcWTh, fcWTl, fcb, nullptr, h1h, h1l, HID1, K1P);

  // --- layer 1: t1 = h1 @ W1 (fp32); h2 = relu(agg(t1)+..) planes [NN][224] ---
  gemm_ares_kernel<K1P, false, false, false><<<MBLK, 256, 0, stream>>>(
      h1h, h1l, W1Th, W1Tl, nullptr, t1, nullptr, nullptr, HID2, HID2);
  agg_gather_kernel<HID2, K2P, 1, true><<<(NN + 3) / 4, 256, 0, stream>>>(
      rowptr, srcS, wS, t1, dinv, b1, nullptr, h2h, h2l);

  // --- layer 2: t2 = h2 @ W2 (fp32); out = relu(agg(t2)+..) fp32 ---
  gemm_ares_kernel<K2P, false, false, false><<<MBLK, 256, 0, stream>>>(
      h2h, h2l, W2Th, W2Tl, nullptr, t2, nullptr, nullptr, OUT_FT, OUT_FT);
  agg_gather_kernel<OUT_FT, OUT_FT, 2, false><<<(NN + 7) / 8, 256, 0, stream>>>(
      rowptr, srcS, wS, t2, dinv, b2, (float*)d_out, nullptr, nullptr);
}

// Round 15
// 264.501 us; speedup vs baseline: 1.2383x; 1.0867x over previous
//
#include <hip/hip_runtime.h>

// GCN encoder: h1 = relu(x@fcW+fcb); h2 = relu(gcn(h1,W1,b1)); out = relu(gcn(h2,W2,b2))
// gcn(x,W,b)[i] = sum_{e:dst=i} (x@W)[src_e]*norm_e + (x@W)[i]*dinv[i]^2 + b
// Aggregation: dst-sorted CSR on device; per-node float4 gather.
// GEMM: split-bf16 MFMA, pre-split zero-K-padded planes (A[M][KAP],
// BT[N][KAP]). Round-12 structure (coalesced LDS staging, 64x64 tile,
// 4 waves 2x2, many blocks) -- best measured (fc 46us; rounds 13/14's
// direct-gather variants regressed to 91/62us). Single change: BK 32->64
// (KAP padded to 64-multiples) => HALF the vmcnt(0)+barrier drains per
// K-loop and 2x loads in flight per drain (round 12 was latency-bound at
// 1.7 TB/s fetch, 3.6x its BW floor). LDK=BK+4 keeps frag reads 2-way free.
// hipMemsetAsync replaced by a grid-wide zero kernel (a 44us
// fillBufferAligned appeared in-stream in rounds 12-14 profiles).
// No min-waves in __launch_bounds__ (rounds 5/6: hipcc spills to meet it).

typedef unsigned short us;

namespace {
constexpr int NN = 20000;
constexpr int NE = 320000;
constexpr int IN_FT = 256, HID1 = 400, HID2 = 200, OUT_FT = 128;
constexpr int K1P = 448;  // HID1 padded to 64
constexpr int K2P = 256;  // HID2 padded to 64
using short8v = __attribute__((ext_vector_type(8))) short;
using f32x4 = __attribute__((ext_vector_type(4))) float;
}

__device__ __forceinline__ us f2bf(float f) {
  unsigned int u = __float_as_uint(f);
  u += 0x7FFFu + ((u >> 16) & 1u);  // round-to-nearest-even
  return (us)(u >> 16);
}
__device__ __forceinline__ float bf2f(us h) {
  return __uint_as_float(((unsigned int)h) << 16);
}

// fast zero of n float4-aligned words
__global__ __launch_bounds__(256) void zero_kernel(float4* __restrict__ p, int n4) {
  int i = blockIdx.x * 256 + threadIdx.x;
  if (i < n4) p[i] = make_float4(0.f, 0.f, 0.f, 0.f);
}

// deg (weighted, +1 self loop) and integer count per dst in one pass
__global__ __launch_bounds__(256) void deg_count_kernel(const int* __restrict__ dst,
                                                        const float* __restrict__ ew,
                                                        float* __restrict__ deg,
                                                        int* __restrict__ cnt) {
  int tid = blockIdx.x * 256 + threadIdx.x;
  if (tid < NE) {
    int d = dst[tid];
    unsafeAtomicAdd(&deg[d], ew[tid]);
    atomicAdd(&cnt[d], 1);
  } else if (tid < NE + NN) {
    unsafeAtomicAdd(&deg[tid - NE], 1.0f);  // self-loop weight 1
  }
}

// single block: deg -> dinv in place, exclusive scan count -> rowptr,
// count overwritten with exclusive prefix (scatter fill cursor).
__global__ __launch_bounds__(1024) void scan_dinv_kernel(int* __restrict__ count,
                                                         int* __restrict__ rowptr,
                                                         float* __restrict__ deg) {
  constexpr int CHUNK = (NN + 1023) / 1024;  // 20
  __shared__ int partial[1024];
  const int t = threadIdx.x;
  const int base = t * CHUNK;
#pragma unroll
  for (int i = 0; i < CHUNK; ++i) {
    int idx = base + i;
    if (idx < NN) {
      float d = deg[idx];
      deg[idx] = d > 0.f ? rsqrtf(d) : 0.f;
    }
  }
  int s = 0;
#pragma unroll
  for (int i = 0; i < CHUNK; ++i) {
    int idx = base + i;
    if (idx < NN) s += count[idx];
  }
  partial[t] = s;
  __syncthreads();
  for (int off = 1; off < 1024; off <<= 1) {
    int v = 0;
    if (t >= off) v = partial[t - off];
    __syncthreads();
    if (t >= off) partial[t] += v;
    __syncthreads();
  }
  int excl = partial[t] - s;
#pragma unroll
  for (int i = 0; i < CHUNK; ++i) {
    int idx = base + i;
    if (idx < NN) {
      int c = count[idx];
      rowptr[idx] = excl;
      count[idx] = excl;  // scatter fill cursor
      excl += c;
    }
  }
  if (t == 1023) rowptr[NN] = partial[1023];
}

// scatter edges into dst-sorted order, computing norm inline
__global__ __launch_bounds__(256) void scatter_kernel(const int* __restrict__ src,
                                                      const int* __restrict__ dst,
                                                      const float* __restrict__ ew,
                                                      const float* __restrict__ dinv,
                                                      int* __restrict__ fill,
                                                      int* __restrict__ srcS,
                                                      float* __restrict__ wS) {
  int e = blockIdx.x * 256 + threadIdx.x;
  if (e >= NE) return;
  int s = src[e], d = dst[e];
  int pos = atomicAdd(&fill[d], 1);
  srcS[pos] = s;
  wS[pos] = dinv[s] * ew[e] * dinv[d];
}

// one prep kernel: split x into hi/lo planes (8 elems/thread), then
// transpose+split all three weights into [N][Kpad] hi/lo planes (1 elem/thr)
__global__ __launch_bounds__(256) void prep_kernel(
    const float* __restrict__ x, us* __restrict__ xh, us* __restrict__ xl,
    const float* __restrict__ fcW, const float* __restrict__ W1,
    const float* __restrict__ W2,
    us* __restrict__ fcWTh, us* __restrict__ fcWTl,
    us* __restrict__ W1Th, us* __restrict__ W1Tl,
    us* __restrict__ W2Th, us* __restrict__ W2Tl) {
  constexpr int NXS = NN * IN_FT / 8;  // 640000 x-split items
  constexpr int N0 = HID1 * IN_FT;     // 102400
  constexpr int N1 = HID2 * K1P;       // 89600
  constexpr int N2 = OUT_FT * K2P;     // 32768
  int idx = blockIdx.x * 256 + threadIdx.x;
  if (idx < NXS) {
    const float4 v0 = reinterpret_cast<const float4*>(x)[idx * 2];
    const float4 v1 = reinterpret_cast<const float4*>(x)[idx * 2 + 1];
    const float v[8] = {v0.x, v0.y, v0.z, v0.w, v1.x, v1.y, v1.z, v1.w};
    short8v h, l;
#pragma unroll
    for (int j = 0; j < 8; ++j) {
      us hh = f2bf(v[j]);
      h[j] = (short)hh;
      l[j] = (short)f2bf(v[j] - bf2f(hh));
    }
    reinterpret_cast<short8v*>(xh)[idx] = h;
    reinterpret_cast<short8v*>(xl)[idx] = l;
    return;
  }
  int widx = idx - NXS;
  float v;
  us *th, *tl;
  int o;
  if (widx < N0) {
    o = widx;
    int n = o / IN_FT, k = o - n * IN_FT;  // Kpad == K == 256
    v = fcW[(size_t)k * HID1 + n];
    th = fcWTh; tl = fcWTl;
  } else if (widx < N0 + N1) {
    o = widx - N0;
    int n = o / K1P, k = o - n * K1P;
    v = (k < HID1) ? W1[(size_t)k * HID2 + n] : 0.f;
    th = W1Th; tl = W1Tl;
  } else if (widx < N0 + N1 + N2) {
    o = widx - N0 - N1;
    int n = o / K2P, k = o - n * K2P;
    v = (k < HID2) ? W2[(size_t)k * OUT_FT + n] : 0.f;
    th = W2Th; tl = W2Tl;
  } else {
    return;
  }
  us h = f2bf(v);
  th[o] = h;
  tl[o] = f2bf(v - bf2f(h));
}

// C[M,N] = A[M,KAP] @ BT[N,KAP]^T from pre-split zero-K-padded planes.
// 64x64 tile, BK=64 (KAP % 64 == 0), 4 waves (2x2), wave = 2x2 16x16 frags.
// SPLIT: write Ch/Cl planes (row stride NPAD, zero-fill cols [N,NPAD)).
template <int KAP, bool BIAS, bool RELU, bool SPLIT>
__global__ __launch_bounds__(256) void gemm64_kernel(
    const us* __restrict__ Ah, const us* __restrict__ Al,
    const us* __restrict__ BTh, const us* __restrict__ BTl,
    const float* __restrict__ bias, float* __restrict__ Cf,
    us* __restrict__ Ch, us* __restrict__ Cl,
    int M, int N, int NPAD) {
  constexpr int BK = 64;
  constexpr int LDK = BK + 4;  // frag reads spread 2-way max (free)
  __shared__ us Ash[64][LDK];
  __shared__ us Asl[64][LDK];
  __shared__ us Bsh[64][LDK];
  __shared__ us Bsl[64][LDK];
  const int tid = threadIdx.x;
  const int lane = tid & 63;
  const int wid = tid >> 6;
  const int wm = wid >> 1, wn = wid & 1;  // 2x2 wave grid
  const int m0 = blockIdx.y * 64, n0 = blockIdx.x * 64;
  const int sr = tid >> 2, sko = (tid & 3) * 16;  // staging: row, k-offset
  const int arow = m0 + sr;
  const int brow = n0 + sr;
  const int l15 = lane & 15, kg = lane >> 4;
  const short8v zv = {0, 0, 0, 0, 0, 0, 0, 0};

  f32x4 acc[2][2];
#pragma unroll
  for (int i = 0; i < 2; ++i)
#pragma unroll
    for (int j = 0; j < 2; ++j)
#pragma unroll
      for (int c = 0; c < 4; ++c) acc[i][j][c] = 0.f;

  for (int k0 = 0; k0 < KAP; k0 += BK) {
    // stage: 16 contiguous k per thread per plane (2 x b128), coalesced
    short8v a0h = zv, a1h = zv, a0l = zv, a1l = zv;
    short8v b0h = zv, b1h = zv, b0l = zv, b1l = zv;
    if (arow < M) {
      const size_t off = (size_t)arow * KAP + k0 + sko;
      a0h = *reinterpret_cast<const short8v*>(Ah + off);
      a1h = *reinterpret_cast<const short8v*>(Ah + off + 8);
      a0l = *reinterpret_cast<const short8v*>(Al + off);
      a1l = *reinterpret_cast<const short8v*>(Al + off + 8);
    }
    if (brow < N) {
      const size_t off = (size_t)brow * KAP + k0 + sko;
      b0h = *reinterpret_cast<const short8v*>(BTh + off);
      b1h = *reinterpret_cast<const short8v*>(BTh + off + 8);
      b0l = *reinterpret_cast<const short8v*>(BTl + off);
      b1l = *reinterpret_cast<const short8v*>(BTl + off + 8);
    }
    *reinterpret_cast<short8v*>(&Ash[sr][sko]) = a0h;
    *reinterpret_cast<short8v*>(&Ash[sr][sko + 8]) = a1h;
    *reinterpret_cast<short8v*>(&Asl[sr][sko]) = a0l;
    *reinterpret_cast<short8v*>(&Asl[sr][sko + 8]) = a1l;
    *reinterpret_cast<short8v*>(&Bsh[sr][sko]) = b0h;
    *reinterpret_cast<short8v*>(&Bsh[sr][sko + 8]) = b1h;
    *reinterpret_cast<short8v*>(&Bsl[sr][sko]) = b0l;
    *reinterpret_cast<short8v*>(&Bsl[sr][sko + 8]) = b1l;
    __syncthreads();
#pragma unroll
    for (int kc = 0; kc < BK; kc += 32) {
      short8v afh[2], afl[2], bfh[2], bfl[2];
#pragma unroll
      for (int mf = 0; mf < 2; ++mf) {
        const int r = wm * 32 + mf * 16 + l15;
        afh[mf] = *reinterpret_cast<const short8v*>(&Ash[r][kc + kg * 8]);
        afl[mf] = *reinterpret_cast<const short8v*>(&Asl[r][kc + kg * 8]);
      }
#pragma unroll
      for (int nf = 0; nf < 2; ++nf) {
        const int c = wn * 32 + nf * 16 + l15;
        bfh[nf] = *reinterpret_cast<const short8v*>(&Bsh[c][kc + kg * 8]);
        bfl[nf] = *reinterpret_cast<const short8v*>(&Bsl[c][kc + kg * 8]);
      }
#pragma unroll
      for (int mf = 0; mf < 2; ++mf)
#pragma unroll
        for (int nf = 0; nf < 2; ++nf) {
          acc[mf][nf] = __builtin_amdgcn_mfma_f32_16x16x32_bf16(afh[mf], bfh[nf], acc[mf][nf], 0, 0, 0);
          acc[mf][nf] = __builtin_amdgcn_mfma_f32_16x16x32_bf16(afh[mf], bfl[nf], acc[mf][nf], 0, 0, 0);
          acc[mf][nf] = __builtin_amdgcn_mfma_f32_16x16x32_bf16(afl[mf], bfh[nf], acc[mf][nf], 0, 0, 0);
        }
    }
    __syncthreads();
  }

  // epilogue: C/D layout col=lane&15, row=(lane>>4)*4+reg (guide §3, m89/m91)
#pragma unroll
  for (int nf = 0; nf < 2; ++nf) {
    const int col = n0 + wn * 32 + nf * 16 + l15;
    float bb = 0.f;
    if (BIAS && col < N) bb = bias[col];
#pragma unroll
    for (int mf = 0; mf < 2; ++mf) {
      const int rbase = m0 + wm * 32 + mf * 16 + kg * 4;
#pragma unroll
      for (int i = 0; i < 4; ++i) {
        const int row = rbase + i;
        if (row >= M) continue;
        if (col < N) {
          float v = acc[mf][nf][i];
          if (BIAS) v += bb;
          if (RELU) v = fmaxf(v, 0.f);
          if (SPLIT) {
            us h = f2bf(v);
            Ch[(size_t)row * NPAD + col] = h;
            Cl[(size_t)row * NPAD + col] = f2bf(v - bf2f(h));
          } else {
            Cf[(size_t)row * N + col] = v;
          }
        } else if (SPLIT && col < NPAD) {  // zero the K-pad for next GEMM
          Ch[(size_t)row * NPAD + col] = 0;
          Cl[(size_t)row * NPAD + col] = 0;
        }
      }
    }
  }
}

// Fused gather-aggregate + self-loop + bias + relu.
// NPW nodes/wave; F/4 lanes per node, ONE float4 per edge per lane.
// SPLIT: write bf16 hi/lo planes with row stride OST, zero-pad cols [F,OST).
template <int F, int OST, int NPW, bool SPLIT>
__global__ __launch_bounds__(256) void agg_gather_kernel(const int* __restrict__ rowptr,
                                                         const int* __restrict__ srcS,
                                                         const float* __restrict__ wS,
                                                         const float* __restrict__ t,
                                                         const float* __restrict__ dinv,
                                                         const float* __restrict__ bias,
                                                         float* __restrict__ out,
                                                         us* __restrict__ oh,
                                                         us* __restrict__ ol) {
  constexpr int LPN = F / 4;     // float4 lanes per node
  constexpr int LPNP = OST / 4;  // lanes incl. pad
  const int wv = threadIdx.x >> 6;
  const int lane = threadIdx.x & 63;
  const int sub = (NPW == 2) ? (lane >> 5) : 0;
  const int l = (NPW == 2) ? (lane & 31) : lane;
  const int node = blockIdx.x * (4 * NPW) + wv * NPW + sub;
  if (node >= NN) return;
  if (l >= LPN) {
    if (SPLIT && l < LPNP) {  // zero the K-pad for the next GEMM
      ushort4 z = make_ushort4(0, 0, 0, 0);
      *reinterpret_cast<ushort4*>(oh + (size_t)node * OST + l * 4) = z;
      *reinterpret_cast<ushort4*>(ol + (size_t)node * OST + l * 4) = z;
    }
    return;  // no barriers/shuffles below: safe exit
  }
  const int beg = rowptr[node], end = rowptr[node + 1];
  const size_t fo = (size_t)l * 4;
  float4 acc0 = make_float4(0.f, 0.f, 0.f, 0.f);
  float4 acc1 = make_float4(0.f, 0.f, 0.f, 0.f);
  int j = beg;
  for (; j + 1 < end; j += 2) {  // 2-way unroll: independent load->FMA chains
    const int s0 = srcS[j], s1 = srcS[j + 1];
    const float w0 = wS[j], w1 = wS[j + 1];
    const float4 v0 = *reinterpret_cast<const float4*>(t + (size_t)s0 * F + fo);
    const float4 v1 = *reinterpret_cast<const float4*>(t + (size_t)s1 * F + fo);
    acc0.x = fmaf(v0.x, w0, acc0.x); acc0.y = fmaf(v0.y, w0, acc0.y);
    acc0.z = fmaf(v0.z, w0, acc0.z); acc0.w = fmaf(v0.w, w0, acc0.w);
    acc1.x = fmaf(v1.x, w1, acc1.x); acc1.y = fmaf(v1.y, w1, acc1.y);
    acc1.z = fmaf(v1.z, w1, acc1.z); acc1.w = fmaf(v1.w, w1, acc1.w);
  }
  if (j < end) {
    const int s0 = srcS[j];
    const float w0 = wS[j];
    const float4 v0 = *reinterpret_cast<const float4*>(t + (size_t)s0 * F + fo);
    acc0.x = fmaf(v0.x, w0, acc0.x); acc0.y = fmaf(v0.y, w0, acc0.y);
    acc0.z = fmaf(v0.z, w0, acc0.z); acc0.w = fmaf(v0.w, w0, acc0.w);
  }
  const float di = dinv[node];
  const float sw = di * di;
  const float4 tv = *reinterpret_cast<const float4*>(t + (size_t)node * F + fo);
  const float4 bb = *reinterpret_cast<const float4*>(bias + fo);
  float4 o;
  o.x = fmaxf(fmaf(tv.x, sw, acc0.x + acc1.x) + bb.x, 0.f);
  o.y = fmaxf(fmaf(tv.y, sw, acc0.y + acc1.y) + bb.y, 0.f);
  o.z = fmaxf(fmaf(tv.z, sw, acc0.z + acc1.z) + bb.z, 0.f);
  o.w = fmaxf(fmaf(tv.w, sw, acc0.w + acc1.w) + bb.w, 0.f);
  if (SPLIT) {
    ushort4 hv, lv;
    hv.x = f2bf(o.x); lv.x = f2bf(o.x - bf2f(hv.x));
    hv.y = f2bf(o.y); lv.y = f2bf(o.y - bf2f(hv.y));
    hv.z = f2bf(o.z); lv.z = f2bf(o.z - bf2f(hv.z));
    hv.w = f2bf(o.w); lv.w = f2bf(o.w - bf2f(hv.w));
    *reinterpret_cast<ushort4*>(oh + (size_t)node * OST + fo) = hv;
    *reinterpret_cast<ushort4*>(ol + (size_t)node * OST + fo) = lv;
  } else {
    *reinterpret_cast<float4*>(out + (size_t)node * F + fo) = o;
  }
}

extern "C" void kernel_launch(void* const* d_in, const int* in_sizes, int n_in,
                              void* d_out, int out_size, void* d_ws, size_t ws_size,
                              hipStream_t stream) {
  const float* x = (const float*)d_in[0];
  const int* ei = (const int*)d_in[1];  // int32 per harness conversion
  const float* ea = (const float*)d_in[2];
  const float* fcW = (const float*)d_in[3];
  const float* fcb = (const float*)d_in[4];
  const float* W1 = (const float*)d_in[5];
  const float* b1 = (const float*)d_in[6];
  const float* W2 = (const float*)d_in[7];
  const float* b2 = (const float*)d_in[8];
  const int* srcIdx = ei;       // edge_index[0]
  const int* dstIdx = ei + NE;  // edge_index[1]

  char* ws = (char*)d_ws;
  constexpr size_t KB_ = 1u << 10;
  float* dinv = (float*)(ws);                    // 80000 B (doubles as deg)
  int* cnt = (int*)(ws + 80000);                 // 80000 B (count -> cursor)
  int* rowptr = (int*)(ws + 160000);             // 80004 B
  int* srcS = (int*)(ws + 256 * KB_);            // 1.28 MB
  float* wS = (float*)(ws + 1536 * KB_);         // 1.28 MB
  us* fcWTh = (us*)(ws + 2880 * KB_);            // 204800 B
  us* fcWTl = (us*)(ws + 3088 * KB_);
  us* W1Th = (us*)(ws + 3296 * KB_);             // 200x448x2 = 179200 B
  us* W1Tl = (us*)(ws + 3472 * KB_);
  us* W2Th = (us*)(ws + 3648 * KB_);             // 128x256x2 = 65536 B
  us* W2Tl = (us*)(ws + 3712 * KB_);             // ends exactly at 3776 KB
  us* xh = (us*)(ws + 3776 * KB_);               // 10.24 MB
  us* xl = (us*)(ws + 13784 * KB_);              // ends ~23.8 MB
  us* h1h = (us*)(ws + 23800 * KB_);             // 20000x448x2 = 17.92 MB
  us* h1l = (us*)(ws + 41350 * KB_);             // ends ~57.5 MB (peak)
  float* t1 = (float*)(ws + 3776 * KB_);         // 16 MB (x dead); also t2
  us* h2h = (us*)(ws + 23800 * KB_);             // 10.24 MB (h1 dead)
  us* h2l = (us*)(ws + 33800 * KB_);
  float* t2 = (float*)(ws + 3776 * KB_);         // 10.24 MB (t1 dead)

  // --- normalization + CSR (shared by both GCN layers) ---
  zero_kernel<<<(40000 / 4 + 255) / 256, 256, 0, stream>>>((float4*)ws, 40000 / 4);
  deg_count_kernel<<<(NE + NN + 255) / 256, 256, 0, stream>>>(dstIdx, ea, dinv, cnt);
  scan_dinv_kernel<<<1, 1024, 0, stream>>>(cnt, rowptr, dinv);
  scatter_kernel<<<(NE + 255) / 256, 256, 0, stream>>>(srcIdx, dstIdx, ea, dinv, cnt, srcS, wS);

  // --- one-time operand prep: split x + transpose/split all weights ---
  {
    constexpr int TOT = NN * IN_FT / 8 + HID1 * IN_FT + HID2 * K1P + OUT_FT * K2P;
    prep_kernel<<<(TOT + 255) / 256, 256, 0, stream>>>(
        x, xh, xl, fcW, W1, W2, fcWTh, fcWTl, W1Th, W1Tl, W2Th, W2Tl);
  }

  const int MBLK = (NN + 63) / 64;  // 313 row blocks

  // --- h1 = relu(x @ fcW + fcb), bf16 hi/lo planes [NN][448] ---
  gemm64_kernel<IN_FT, true, true, true><<<dim3((HID1 + 63) / 64, MBLK), 256, 0, stream>>>(
      xh, xl, fcWTh, fcWTl, fcb, nullptr, h1h, h1l, NN, HID1, K1P);

  // --- layer 1: t1 = h1 @ W1 (fp32); h2 = relu(agg(t1)+..) planes [NN][256] ---
  gemm64_kernel<K1P, false, false, false><<<dim3((HID2 + 63) / 64, MBLK), 256, 0, stream>>>(
      h1h, h1l, W1Th, W1Tl, nullptr, t1, nullptr, nullptr, NN, HID2, HID2);
  agg_gather_kernel<HID2, K2P, 1, true><<<(NN + 3) / 4, 256, 0, stream>>>(
      rowptr, srcS, wS, t1, dinv, b1, nullptr, h2h, h2l);

  // --- layer 2: t2 = h2 @ W2 (fp32); out = relu(agg(t2)+..) fp32 ---
  gemm64_kernel<K2P, false, false, false><<<dim3((OUT_FT + 63) / 64, MBLK), 256, 0, stream>>>(
      h2h, h2l, W2Th, W2Tl, nullptr, t2, nullptr, nullptr, NN, OUT_FT, OUT_FT);
  agg_gather_kernel<OUT_FT, OUT_FT, 2, false><<<(NN + 7) / 8, 256, 0, stream>>>(
      rowptr, srcS, wS, t2, dinv, b2, (float*)d_out, nullptr, nullptr);
}

// Round 16
// 216.663 us; speedup vs baseline: 1.5117x; 1.2208x over previous
//
#include <hip/hip_runtime.h>

// GCN encoder: h1 = relu(x@fcW+fcb); h2 = relu(gcn(h1,W1,b1)); out = relu(gcn(h2,W2,b2))
// gcn(x,W,b)[i] = sum_{e:dst=i} (x@W)[src_e]*norm_e + (x@W)[i]*dinv[i]^2 + b
// Aggregation: dst-sorted CSR on device; per-node float4 gather.
// GEMM: split-bf16 MFMA, pre-split zero-K-padded planes, 64x64 tile, BK=64
// (round 15: halving barrier drains got GEMMs under 58us each).
// CSR scan: 3-phase parallel (80-block partial sums + tiny scan + 80-block
// write) -- round 15's single-block scan_dinv was the TOP dispatch at 58us
// (0.15% occupancy, one CU working, 255 idle).
// No min-waves in __launch_bounds__ (rounds 5/6: hipcc spills to meet it).

typedef unsigned short us;

namespace {
constexpr int NN = 20000;
constexpr int NE = 320000;
constexpr int IN_FT = 256, HID1 = 400, HID2 = 200, OUT_FT = 128;
constexpr int K1P = 448;  // HID1 padded to 64
constexpr int K2P = 256;  // HID2 padded to 64
constexpr int SBLK = 80;       // scan blocks
constexpr int SCHUNK = 250;    // elements per scan block (80*250 = 20000)
using short8v = __attribute__((ext_vector_type(8))) short;
using f32x4 = __attribute__((ext_vector_type(4))) float;
}

__device__ __forceinline__ us f2bf(float f) {
  unsigned int u = __float_as_uint(f);
  u += 0x7FFFu + ((u >> 16) & 1u);  // round-to-nearest-even
  return (us)(u >> 16);
}
__device__ __forceinline__ float bf2f(us h) {
  return __uint_as_float(((unsigned int)h) << 16);
}

// fast zero of n float4-aligned words
__global__ __launch_bounds__(256) void zero_kernel(float4* __restrict__ p, int n4) {
  int i = blockIdx.x * 256 + threadIdx.x;
  if (i < n4) p[i] = make_float4(0.f, 0.f, 0.f, 0.f);
}

// deg (weighted, +1 self loop) and integer count per dst in one pass
__global__ __launch_bounds__(256) void deg_count_kernel(const int* __restrict__ dst,
                                                        const float* __restrict__ ew,
                                                        float* __restrict__ deg,
                                                        int* __restrict__ cnt) {
  int tid = blockIdx.x * 256 + threadIdx.x;
  if (tid < NE) {
    int d = dst[tid];
    unsafeAtomicAdd(&deg[d], ew[tid]);
    atomicAdd(&cnt[d], 1);
  } else if (tid < NE + NN) {
    unsafeAtomicAdd(&deg[tid - NE], 1.0f);  // self-loop weight 1
  }
}

// scan phase B: per-block count sums (tree reduce) + dinv elementwise
__global__ __launch_bounds__(256) void blocksum_dinv_kernel(const int* __restrict__ count,
                                                            int* __restrict__ bsum,
                                                            float* __restrict__ deg) {
  __shared__ int sdata[256];
  const int b = blockIdx.x, t = threadIdx.x;
  const int base = b * SCHUNK;
  int v = 0;
  if (t < SCHUNK) {
    const int i = base + t;
    v = count[i];
    float d = deg[i];
    deg[i] = d > 0.f ? rsqrtf(d) : 0.f;  // in place: deg -> dinv
  }
  sdata[t] = v;
  __syncthreads();
#pragma unroll
  for (int off = 128; off > 0; off >>= 1) {
    if (t < off) sdata[t] += sdata[t + off];
    __syncthreads();
  }
  if (t == 0) bsum[b] = sdata[0];
}

// scan phase C: exclusive scan of the 80 block sums (trivial single block)
__global__ __launch_bounds__(128) void scanb_kernel(const int* __restrict__ bsum,
                                                    int* __restrict__ bpre) {
  __shared__ int s[SBLK];
  const int t = threadIdx.x;
  if (t < SBLK) s[t] = bsum[t];
  __syncthreads();
  for (int off = 1; off < SBLK; off <<= 1) {
    int v = 0;
    if (t < SBLK && t >= off) v = s[t - off];
    __syncthreads();
    if (t < SBLK && t >= off) s[t] += v;
    __syncthreads();
  }
  if (t < SBLK) bpre[t] = s[t] - bsum[t];  // exclusive prefix
}

// scan phase D: local exclusive scan + block offset -> rowptr, cursor
__global__ __launch_bounds__(256) void rowptr_kernel(const int* __restrict__ bpre,
                                                     int* __restrict__ count,  // read, then overwritten as cursor
                                                     int* __restrict__ rowptr) {
  __shared__ int s[256];
  const int b = blockIdx.x, t = threadIdx.x;
  const int base = b * SCHUNK;
  const int v = (t < SCHUNK) ? count[base + t] : 0;
  s[t] = v;
  __syncthreads();
#pragma unroll
  for (int off = 1; off < 256; off <<= 1) {
    int u = 0;
    if (t >= off) u = s[t - off];
    __syncthreads();
    if (t >= off) s[t] += u;
    __syncthreads();
  }
  const int excl = s[t] - v + bpre[b];
  if (t < SCHUNK) {
    rowptr[base + t] = excl;
    count[base + t] = excl;  // scatter fill cursor
  }
  if (b == SBLK - 1 && t == 0) rowptr[NN] = NE;  // total is static
}

// scatter edges into dst-sorted order, computing norm inline
__global__ __launch_bounds__(256) void scatter_kernel(const int* __restrict__ src,
                                                      const int* __restrict__ dst,
                                                      const float* __restrict__ ew,
                                                      const float* __restrict__ dinv,
                                                      int* __restrict__ fill,
                                                      int* __restrict__ srcS,
                                                      float* __restrict__ wS) {
  int e = blockIdx.x * 256 + threadIdx.x;
  if (e >= NE) return;
  int s = src[e], d = dst[e];
  int pos = atomicAdd(&fill[d], 1);
  srcS[pos] = s;
  wS[pos] = dinv[s] * ew[e] * dinv[d];
}

// one prep kernel: split x into hi/lo planes (8 elems/thread), then
// transpose+split all three weights into [N][Kpad] hi/lo planes (1 elem/thr)
__global__ __launch_bounds__(256) void prep_kernel(
    const float* __restrict__ x, us* __restrict__ xh, us* __restrict__ xl,
    const float* __restrict__ fcW, const float* __restrict__ W1,
    const float* __restrict__ W2,
    us* __restrict__ fcWTh, us* __restrict__ fcWTl,
    us* __restrict__ W1Th, us* __restrict__ W1Tl,
    us* __restrict__ W2Th, us* __restrict__ W2Tl) {
  constexpr int NXS = NN * IN_FT / 8;  // 640000 x-split items
  constexpr int N0 = HID1 * IN_FT;     // 102400
  constexpr int N1 = HID2 * K1P;       // 89600
  constexpr int N2 = OUT_FT * K2P;     // 32768
  int idx = blockIdx.x * 256 + threadIdx.x;
  if (idx < NXS) {
    const float4 v0 = reinterpret_cast<const float4*>(x)[idx * 2];
    const float4 v1 = reinterpret_cast<const float4*>(x)[idx * 2 + 1];
    const float v[8] = {v0.x, v0.y, v0.z, v0.w, v1.x, v1.y, v1.z, v1.w};
    short8v h, l;
#pragma unroll
    for (int j = 0; j < 8; ++j) {
      us hh = f2bf(v[j]);
      h[j] = (short)hh;
      l[j] = (short)f2bf(v[j] - bf2f(hh));
    }
    reinterpret_cast<short8v*>(xh)[idx] = h;
    reinterpret_cast<short8v*>(xl)[idx] = l;
    return;
  }
  int widx = idx - NXS;
  float v;
  us *th, *tl;
  int o;
  if (widx < N0) {
    o = widx;
    int n = o / IN_FT, k = o - n * IN_FT;  // Kpad == K == 256
    v = fcW[(size_t)k * HID1 + n];
    th = fcWTh; tl = fcWTl;
  } else if (widx < N0 + N1) {
    o = widx - N0;
    int n = o / K1P, k = o - n * K1P;
    v = (k < HID1) ? W1[(size_t)k * HID2 + n] : 0.f;
    th = W1Th; tl = W1Tl;
  } else if (widx < N0 + N1 + N2) {
    o = widx - N0 - N1;
    int n = o / K2P, k = o - n * K2P;
    v = (k < HID2) ? W2[(size_t)k * OUT_FT + n] : 0.f;
    th = W2Th; tl = W2Tl;
  } else {
    return;
  }
  us h = f2bf(v);
  th[o] = h;
  tl[o] = f2bf(v - bf2f(h));
}

// C[M,N] = A[M,KAP] @ BT[N,KAP]^T from pre-split zero-K-padded planes.
// 64x64 tile, BK=64 (KAP % 64 == 0), 4 waves (2x2), wave = 2x2 16x16 frags.
// SPLIT: write Ch/Cl planes (row stride NPAD, zero-fill cols [N,NPAD)).
template <int KAP, bool BIAS, bool RELU, bool SPLIT>
__global__ __launch_bounds__(256) void gemm64_kernel(
    const us* __restrict__ Ah, const us* __restrict__ Al,
    const us* __restrict__ BTh, const us* __restrict__ BTl,
    const float* __restrict__ bias, float* __restrict__ Cf,
    us* __restrict__ Ch, us* __restrict__ Cl,
    int M, int N, int NPAD) {
  constexpr int BK = 64;
  constexpr int LDK = BK + 4;  // frag reads spread 2-way max (free)
  __shared__ us Ash[64][LDK];
  __shared__ us Asl[64][LDK];
  __shared__ us Bsh[64][LDK];
  __shared__ us Bsl[64][LDK];
  const int tid = threadIdx.x;
  const int lane = tid & 63;
  const int wid = tid >> 6;
  const int wm = wid >> 1, wn = wid & 1;  // 2x2 wave grid
  const int m0 = blockIdx.y * 64, n0 = blockIdx.x * 64;
  const int sr = tid >> 2, sko = (tid & 3) * 16;  // staging: row, k-offset
  const int arow = m0 + sr;
  const int brow = n0 + sr;
  const int l15 = lane & 15, kg = lane >> 4;
  const short8v zv = {0, 0, 0, 0, 0, 0, 0, 0};

  f32x4 acc[2][2];
#pragma unroll
  for (int i = 0; i < 2; ++i)
#pragma unroll
    for (int j = 0; j < 2; ++j)
#pragma unroll
      for (int c = 0; c < 4; ++c) acc[i][j][c] = 0.f;

  for (int k0 = 0; k0 < KAP; k0 += BK) {
    // stage: 16 contiguous k per thread per plane (2 x b128), coalesced
    short8v a0h = zv, a1h = zv, a0l = zv, a1l = zv;
    short8v b0h = zv, b1h = zv, b0l = zv, b1l = zv;
    if (arow < M) {
      const size_t off = (size_t)arow * KAP + k0 + sko;
      a0h = *reinterpret_cast<const short8v*>(Ah + off);
      a1h = *reinterpret_cast<const short8v*>(Ah + off + 8);
      a0l = *reinterpret_cast<const short8v*>(Al + off);
      a1l = *reinterpret_cast<const short8v*>(Al + off + 8);
    }
    if (brow < N) {
      const size_t off = (size_t)brow * KAP + k0 + sko;
      b0h = *reinterpret_cast<const short8v*>(BTh + off);
      b1h = *reinterpret_cast<const short8v*>(BTh + off + 8);
      b0l = *reinterpret_cast<const short8v*>(BTl + off);
      b1l = *reinterpret_cast<const short8v*>(BTl + off + 8);
    }
    *reinterpret_cast<short8v*>(&Ash[sr][sko]) = a0h;
    *reinterpret_cast<short8v*>(&Ash[sr][sko + 8]) = a1h;
    *reinterpret_cast<short8v*>(&Asl[sr][sko]) = a0l;
    *reinterpret_cast<short8v*>(&Asl[sr][sko + 8]) = a1l;
    *reinterpret_cast<short8v*>(&Bsh[sr][sko]) = b0h;
    *reinterpret_cast<short8v*>(&Bsh[sr][sko + 8]) = b1h;
    *reinterpret_cast<short8v*>(&Bsl[sr][sko]) = b0l;
    *reinterpret_cast<short8v*>(&Bsl[sr][sko + 8]) = b1l;
    __syncthreads();
#pragma unroll
    for (int kc = 0; kc < BK; kc += 32) {
      short8v afh[2], afl[2], bfh[2], bfl[2];
#pragma unroll
      for (int mf = 0; mf < 2; ++mf) {
        const int r = wm * 32 + mf * 16 + l15;
        afh[mf] = *reinterpret_cast<const short8v*>(&Ash[r][kc + kg * 8]);
        afl[mf] = *reinterpret_cast<const short8v*>(&Asl[r][kc + kg * 8]);
      }
#pragma unroll
      for (int nf = 0; nf < 2; ++nf) {
        const int c = wn * 32 + nf * 16 + l15;
        bfh[nf] = *reinterpret_cast<const short8v*>(&Bsh[c][kc + kg * 8]);
        bfl[nf] = *reinterpret_cast<const short8v*>(&Bsl[c][kc + kg * 8]);
      }
#pragma unroll
      for (int mf = 0; mf < 2; ++mf)
#pragma unroll
        for (int nf = 0; nf < 2; ++nf) {
          acc[mf][nf] = __builtin_amdgcn_mfma_f32_16x16x32_bf16(afh[mf], bfh[nf], acc[mf][nf], 0, 0, 0);
          acc[mf][nf] = __builtin_amdgcn_mfma_f32_16x16x32_bf16(afh[mf], bfl[nf], acc[mf][nf], 0, 0, 0);
          acc[mf][nf] = __builtin_amdgcn_mfma_f32_16x16x32_bf16(afl[mf], bfh[nf], acc[mf][nf], 0, 0, 0);
        }
    }
    __syncthreads();
  }

  // epilogue: C/D layout col=lane&15, row=(lane>>4)*4+reg (guide §3, m89/m91)
#pragma unroll
  for (int nf = 0; nf < 2; ++nf) {
    const int col = n0 + wn * 32 + nf * 16 + l15;
    float bb = 0.f;
    if (BIAS && col < N) bb = bias[col];
#pragma unroll
    for (int mf = 0; mf < 2; ++mf) {
      const int rbase = m0 + wm * 32 + mf * 16 + kg * 4;
#pragma unroll
      for (int i = 0; i < 4; ++i) {
        const int row = rbase + i;
        if (row >= M) continue;
        if (col < N) {
          float v = acc[mf][nf][i];
          if (BIAS) v += bb;
          if (RELU) v = fmaxf(v, 0.f);
          if (SPLIT) {
            us h = f2bf(v);
            Ch[(size_t)row * NPAD + col] = h;
            Cl[(size_t)row * NPAD + col] = f2bf(v - bf2f(h));
          } else {
            Cf[(size_t)row * N + col] = v;
          }
        } else if (SPLIT && col < NPAD) {  // zero the K-pad for next GEMM
          Ch[(size_t)row * NPAD + col] = 0;
          Cl[(size_t)row * NPAD + col] = 0;
        }
      }
    }
  }
}

// Fused gather-aggregate + self-loop + bias + relu.
// NPW nodes/wave; F/4 lanes per node, ONE float4 per edge per lane.
// SPLIT: write bf16 hi/lo planes with row stride OST, zero-pad cols [F,OST).
template <int F, int OST, int NPW, bool SPLIT>
__global__ __launch_bounds__(256) void agg_gather_kernel(const int* __restrict__ rowptr,
                                                         const int* __restrict__ srcS,
                                                         const float* __restrict__ wS,
                                                         const float* __restrict__ t,
                                                         const float* __restrict__ dinv,
                                                         const float* __restrict__ bias,
                                                         float* __restrict__ out,
                                                         us* __restrict__ oh,
                                                         us* __restrict__ ol) {
  constexpr int LPN = F / 4;     // float4 lanes per node
  constexpr int LPNP = OST / 4;  // lanes incl. pad
  const int wv = threadIdx.x >> 6;
  const int lane = threadIdx.x & 63;
  const int sub = (NPW == 2) ? (lane >> 5) : 0;
  const int l = (NPW == 2) ? (lane & 31) : lane;
  const int node = blockIdx.x * (4 * NPW) + wv * NPW + sub;
  if (node >= NN) return;
  if (l >= LPN) {
    if (SPLIT && l < LPNP) {  // zero the K-pad for the next GEMM
      ushort4 z = make_ushort4(0, 0, 0, 0);
      *reinterpret_cast<ushort4*>(oh + (size_t)node * OST + l * 4) = z;
      *reinterpret_cast<ushort4*>(ol + (size_t)node * OST + l * 4) = z;
    }
    return;  // no barriers/shuffles below: safe exit
  }
  const int beg = rowptr[node], end = rowptr[node + 1];
  const size_t fo = (size_t)l * 4;
  float4 acc0 = make_float4(0.f, 0.f, 0.f, 0.f);
  float4 acc1 = make_float4(0.f, 0.f, 0.f, 0.f);
  int j = beg;
  for (; j + 1 < end; j += 2) {  // 2-way unroll: independent load->FMA chains
    const int s0 = srcS[j], s1 = srcS[j + 1];
    const float w0 = wS[j], w1 = wS[j + 1];
    const float4 v0 = *reinterpret_cast<const float4*>(t + (size_t)s0 * F + fo);
    const float4 v1 = *reinterpret_cast<const float4*>(t + (size_t)s1 * F + fo);
    acc0.x = fmaf(v0.x, w0, acc0.x); acc0.y = fmaf(v0.y, w0, acc0.y);
    acc0.z = fmaf(v0.z, w0, acc0.z); acc0.w = fmaf(v0.w, w0, acc0.w);
    acc1.x = fmaf(v1.x, w1, acc1.x); acc1.y = fmaf(v1.y, w1, acc1.y);
    acc1.z = fmaf(v1.z, w1, acc1.z); acc1.w = fmaf(v1.w, w1, acc1.w);
  }
  if (j < end) {
    const int s0 = srcS[j];
    const float w0 = wS[j];
    const float4 v0 = *reinterpret_cast<const float4*>(t + (size_t)s0 * F + fo);
    acc0.x = fmaf(v0.x, w0, acc0.x); acc0.y = fmaf(v0.y, w0, acc0.y);
    acc0.z = fmaf(v0.z, w0, acc0.z); acc0.w = fmaf(v0.w, w0, acc0.w);
  }
  const float di = dinv[node];
  const float sw = di * di;
  const float4 tv = *reinterpret_cast<const float4*>(t + (size_t)node * F + fo);
  const float4 bb = *reinterpret_cast<const float4*>(bias + fo);
  float4 o;
  o.x = fmaxf(fmaf(tv.x, sw, acc0.x + acc1.x) + bb.x, 0.f);
  o.y = fmaxf(fmaf(tv.y, sw, acc0.y + acc1.y) + bb.y, 0.f);
  o.z = fmaxf(fmaf(tv.z, sw, acc0.z + acc1.z) + bb.z, 0.f);
  o.w = fmaxf(fmaf(tv.w, sw, acc0.w + acc1.w) + bb.w, 0.f);
  if (SPLIT) {
    ushort4 hv, lv;
    hv.x = f2bf(o.x); lv.x = f2bf(o.x - bf2f(hv.x));
    hv.y = f2bf(o.y); lv.y = f2bf(o.y - bf2f(hv.y));
    hv.z = f2bf(o.z); lv.z = f2bf(o.z - bf2f(hv.z));
    hv.w = f2bf(o.w); lv.w = f2bf(o.w - bf2f(hv.w));
    *reinterpret_cast<ushort4*>(oh + (size_t)node * OST + fo) = hv;
    *reinterpret_cast<ushort4*>(ol + (size_t)node * OST + fo) = lv;
  } else {
    *reinterpret_cast<float4*>(out + (size_t)node * F + fo) = o;
  }
}

extern "C" void kernel_launch(void* const* d_in, const int* in_sizes, int n_in,
                              void* d_out, int out_size, void* d_ws, size_t ws_size,
                              hipStream_t stream) {
  const float* x = (const float*)d_in[0];
  const int* ei = (const int*)d_in[1];  // int32 per harness conversion
  const float* ea = (const float*)d_in[2];
  const float* fcW = (const float*)d_in[3];
  const float* fcb = (const float*)d_in[4];
  const float* W1 = (const float*)d_in[5];
  const float* b1 = (const float*)d_in[6];
  const float* W2 = (const float*)d_in[7];
  const float* b2 = (const float*)d_in[8];
  const int* srcIdx = ei;       // edge_index[0]
  const int* dstIdx = ei + NE;  // edge_index[1]

  char* ws = (char*)d_ws;
  constexpr size_t KB_ = 1u << 10;
  float* dinv = (float*)(ws);                    // 80000 B (doubles as deg)
  int* cnt = (int*)(ws + 80000);                 // 80000 B (count -> cursor)
  int* rowptr = (int*)(ws + 160000);             // 80004 B
  int* bsum = (int*)(ws + 244 * KB_);            // 320 B
  int* bpre = (int*)(ws + 245 * KB_);            // 320 B
  int* srcS = (int*)(ws + 256 * KB_);            // 1.28 MB
  float* wS = (float*)(ws + 1536 * KB_);         // 1.28 MB
  us* fcWTh = (us*)(ws + 2880 * KB_);            // 204800 B
  us* fcWTl = (us*)(ws + 3088 * KB_);
  us* W1Th = (us*)(ws + 3296 * KB_);             // 200x448x2 = 179200 B
  us* W1Tl = (us*)(ws + 3472 * KB_);
  us* W2Th = (us*)(ws + 3648 * KB_);             // 128x256x2 = 65536 B
  us* W2Tl = (us*)(ws + 3712 * KB_);             // ends exactly at 3776 KB
  us* xh = (us*)(ws + 3776 * KB_);               // 10.24 MB
  us* xl = (us*)(ws + 13784 * KB_);              // ends ~23.8 MB
  us* h1h = (us*)(ws + 23800 * KB_);             // 20000x448x2 = 17.92 MB
  us* h1l = (us*)(ws + 41350 * KB_);             // ends ~57.5 MB (peak)
  float* t1 = (float*)(ws + 3776 * KB_);         // 16 MB (x dead); also t2
  us* h2h = (us*)(ws + 23800 * KB_);             // 10.24 MB (h1 dead)
  us* h2l = (us*)(ws + 33800 * KB_);
  float* t2 = (float*)(ws + 3776 * KB_);         // 10.24 MB (t1 dead)

  // --- normalization + CSR (shared by both GCN layers) ---
  zero_kernel<<<(40000 / 4 + 255) / 256, 256, 0, stream>>>((float4*)ws, 40000 / 4);
  deg_count_kernel<<<(NE + NN + 255) / 256, 256, 0, stream>>>(dstIdx, ea, dinv, cnt);
  blocksum_dinv_kernel<<<SBLK, 256, 0, stream>>>(cnt, bsum, dinv);
  scanb_kernel<<<1, 128, 0, stream>>>(bsum, bpre);
  rowptr_kernel<<<SBLK, 256, 0, stream>>>(bpre, cnt, rowptr);
  scatter_kernel<<<(NE + 255) / 256, 256, 0, stream>>>(srcIdx, dstIdx, ea, dinv, cnt, srcS, wS);

  // --- one-time operand prep: split x + transpose/split all weights ---
  {
    constexpr int TOT = NN * IN_FT / 8 + HID1 * IN_FT + HID2 * K1P + OUT_FT * K2P;
    prep_kernel<<<(TOT + 255) / 256, 256, 0, stream>>>(
        x, xh, xl, fcW, W1, W2, fcWTh, fcWTl, W1Th, W1Tl, W2Th, W2Tl);
  }

  const int MBLK = (NN + 63) / 64;  // 313 row blocks

  // --- h1 = relu(x @ fcW + fcb), bf16 hi/lo planes [NN][448] ---
  gemm64_kernel<IN_FT, true, true, true><<<dim3((HID1 + 63) / 64, MBLK), 256, 0, stream>>>(
      xh, xl, fcWTh, fcWTl, fcb, nullptr, h1h, h1l, NN, HID1, K1P);

  // --- layer 1: t1 = h1 @ W1 (fp32); h2 = relu(agg(t1)+..) planes [NN][256] ---
  gemm64_kernel<K1P, false, false, false><<<dim3((HID2 + 63) / 64, MBLK), 256, 0, stream>>>(
      h1h, h1l, W1Th, W1Tl, nullptr, t1, nullptr, nullptr, NN, HID2, HID2);
  agg_gather_kernel<HID2, K2P, 1, true><<<(NN + 3) / 4, 256, 0, stream>>>(
      rowptr, srcS, wS, t1, dinv, b1, nullptr, h2h, h2l);

  // --- layer 2: t2 = h2 @ W2 (fp32); out = relu(agg(t2)+..) fp32 ---
  gemm64_kernel<K2P, false, false, false><<<dim3((OUT_FT + 63) / 64, MBLK), 256, 0, stream>>>(
      h2h, h2l, W2Th, W2Tl, nullptr, t2, nullptr, nullptr, NN, OUT_FT, OUT_FT);
  agg_gather_kernel<OUT_FT, OUT_FT, 2, false><<<(NN + 7) / 8, 256, 0, stream>>>(
      rowptr, srcS, wS, t2, dinv, b2, (float*)d_out, nullptr, nullptr);
}

// Round 17
// 214.730 us; speedup vs baseline: 1.5253x; 1.0090x over previous
//
#include <hip/hip_runtime.h>

// GCN encoder: h1 = relu(x@fcW+fcb); h2 = relu(gcn(h1,W1,b1)); out = relu(gcn(h2,W2,b2))
// gcn(x,W,b)[i] = sum_{e:dst=i} (x@W)[src_e]*norm_e + (x@W)[i]*dinv[i]^2 + b
// Aggregation: dst-sorted CSR on device; per-node float4 gather.
// GEMM: split-bf16 MFMA, pre-split zero-K-padded planes, 64x64 tile, BK=64,
// + REGISTER PREFETCH: next K-step's global loads issued before current
// K-step's compute (gload(k+1); comp(k); sync; sstore; sync) -- round 16
// showed the GEMMs latency-bound (MfmaUtil 10%, 2.5 TB/s fetch, 2.5x HBM
// floor); the load latency now hides under MFMA+LDS-read work.
// CSR scan: 3-phase parallel (round 16: serial scan was 58us top dispatch).
// No min-waves in __launch_bounds__ (rounds 5/6: hipcc spills to meet it).

typedef unsigned short us;

namespace {
constexpr int NN = 20000;
constexpr int NE = 320000;
constexpr int IN_FT = 256, HID1 = 400, HID2 = 200, OUT_FT = 128;
constexpr int K1P = 448;  // HID1 padded to 64
constexpr int K2P = 256;  // HID2 padded to 64
constexpr int SBLK = 80;     // scan blocks
constexpr int SCHUNK = 250;  // elements per scan block (80*250 = 20000)
using short8v = __attribute__((ext_vector_type(8))) short;
using f32x4 = __attribute__((ext_vector_type(4))) float;
}

__device__ __forceinline__ us f2bf(float f) {
  unsigned int u = __float_as_uint(f);
  u += 0x7FFFu + ((u >> 16) & 1u);  // round-to-nearest-even
  return (us)(u >> 16);
}
__device__ __forceinline__ float bf2f(us h) {
  return __uint_as_float(((unsigned int)h) << 16);
}

// fast zero of n float4-aligned words
__global__ __launch_bounds__(256) void zero_kernel(float4* __restrict__ p, int n4) {
  int i = blockIdx.x * 256 + threadIdx.x;
  if (i < n4) p[i] = make_float4(0.f, 0.f, 0.f, 0.f);
}

// deg (weighted, +1 self loop) and integer count per dst in one pass
__global__ __launch_bounds__(256) void deg_count_kernel(const int* __restrict__ dst,
                                                        const float* __restrict__ ew,
                                                        float* __restrict__ deg,
                                                        int* __restrict__ cnt) {
  int tid = blockIdx.x * 256 + threadIdx.x;
  if (tid < NE) {
    int d = dst[tid];
    unsafeAtomicAdd(&deg[d], ew[tid]);
    atomicAdd(&cnt[d], 1);
  } else if (tid < NE + NN) {
    unsafeAtomicAdd(&deg[tid - NE], 1.0f);  // self-loop weight 1
  }
}

// scan phase B: per-block count sums (tree reduce) + dinv elementwise
__global__ __launch_bounds__(256) void blocksum_dinv_kernel(const int* __restrict__ count,
                                                            int* __restrict__ bsum,
                                                            float* __restrict__ deg) {
  __shared__ int sdata[256];
  const int b = blockIdx.x, t = threadIdx.x;
  const int base = b * SCHUNK;
  int v = 0;
  if (t < SCHUNK) {
    const int i = base + t;
    v = count[i];
    float d = deg[i];
    deg[i] = d > 0.f ? rsqrtf(d) : 0.f;  // in place: deg -> dinv
  }
  sdata[t] = v;
  __syncthreads();
#pragma unroll
  for (int off = 128; off > 0; off >>= 1) {
    if (t < off) sdata[t] += sdata[t + off];
    __syncthreads();
  }
  if (t == 0) bsum[b] = sdata[0];
}

// scan phase C: exclusive scan of the 80 block sums (trivial single block)
__global__ __launch_bounds__(128) void scanb_kernel(const int* __restrict__ bsum,
                                                    int* __restrict__ bpre) {
  __shared__ int s[SBLK];
  const int t = threadIdx.x;
  if (t < SBLK) s[t] = bsum[t];
  __syncthreads();
  for (int off = 1; off < SBLK; off <<= 1) {
    int v = 0;
    if (t < SBLK && t >= off) v = s[t - off];
    __syncthreads();
    if (t < SBLK && t >= off) s[t] += v;
    __syncthreads();
  }
  if (t < SBLK) bpre[t] = s[t] - bsum[t];  // exclusive prefix
}

// scan phase D: local exclusive scan + block offset -> rowptr, cursor
__global__ __launch_bounds__(256) void rowptr_kernel(const int* __restrict__ bpre,
                                                     int* __restrict__ count,
                                                     int* __restrict__ rowptr) {
  __shared__ int s[256];
  const int b = blockIdx.x, t = threadIdx.x;
  const int base = b * SCHUNK;
  const int v = (t < SCHUNK) ? count[base + t] : 0;
  s[t] = v;
  __syncthreads();
#pragma unroll
  for (int off = 1; off < 256; off <<= 1) {
    int u = 0;
    if (t >= off) u = s[t - off];
    __syncthreads();
    if (t >= off) s[t] += u;
    __syncthreads();
  }
  const int excl = s[t] - v + bpre[b];
  if (t < SCHUNK) {
    rowptr[base + t] = excl;
    count[base + t] = excl;  // scatter fill cursor
  }
  if (b == SBLK - 1 && t == 0) rowptr[NN] = NE;  // total is static
}

// scatter edges into dst-sorted order, computing norm inline
__global__ __launch_bounds__(256) void scatter_kernel(const int* __restrict__ src,
                                                      const int* __restrict__ dst,
                                                      const float* __restrict__ ew,
                                                      const float* __restrict__ dinv,
                                                      int* __restrict__ fill,
                                                      int* __restrict__ srcS,
                                                      float* __restrict__ wS) {
  int e = blockIdx.x * 256 + threadIdx.x;
  if (e >= NE) return;
  int s = src[e], d = dst[e];
  int pos = atomicAdd(&fill[d], 1);
  srcS[pos] = s;
  wS[pos] = dinv[s] * ew[e] * dinv[d];
}

// one prep kernel: split x into hi/lo planes (8 elems/thread), then
// transpose+split all three weights into [N][Kpad] hi/lo planes (1 elem/thr)
__global__ __launch_bounds__(256) void prep_kernel(
    const float* __restrict__ x, us* __restrict__ xh, us* __restrict__ xl,
    const float* __restrict__ fcW, const float* __restrict__ W1,
    const float* __restrict__ W2,
    us* __restrict__ fcWTh, us* __restrict__ fcWTl,
    us* __restrict__ W1Th, us* __restrict__ W1Tl,
    us* __restrict__ W2Th, us* __restrict__ W2Tl) {
  constexpr int NXS = NN * IN_FT / 8;  // 640000 x-split items
  constexpr int N0 = HID1 * IN_FT;     // 102400
  constexpr int N1 = HID2 * K1P;       // 89600
  constexpr int N2 = OUT_FT * K2P;     // 32768
  int idx = blockIdx.x * 256 + threadIdx.x;
  if (idx < NXS) {
    const float4 v0 = reinterpret_cast<const float4*>(x)[idx * 2];
    const float4 v1 = reinterpret_cast<const float4*>(x)[idx * 2 + 1];
    const float v[8] = {v0.x, v0.y, v0.z, v0.w, v1.x, v1.y, v1.z, v1.w};
    short8v h, l;
#pragma unroll
    for (int j = 0; j < 8; ++j) {
      us hh = f2bf(v[j]);
      h[j] = (short)hh;
      l[j] = (short)f2bf(v[j] - bf2f(hh));
    }
    reinterpret_cast<short8v*>(xh)[idx] = h;
    reinterpret_cast<short8v*>(xl)[idx] = l;
    return;
  }
  int widx = idx - NXS;
  float v;
  us *th, *tl;
  int o;
  if (widx < N0) {
    o = widx;
    int n = o / IN_FT, k = o - n * IN_FT;  // Kpad == K == 256
    v = fcW[(size_t)k * HID1 + n];
    th = fcWTh; tl = fcWTl;
  } else if (widx < N0 + N1) {
    o = widx - N0;
    int n = o / K1P, k = o - n * K1P;
    v = (k < HID1) ? W1[(size_t)k * HID2 + n] : 0.f;
    th = W1Th; tl = W1Tl;
  } else if (widx < N0 + N1 + N2) {
    o = widx - N0 - N1;
    int n = o / K2P, k = o - n * K2P;
    v = (k < HID2) ? W2[(size_t)k * OUT_FT + n] : 0.f;
    th = W2Th; tl = W2Tl;
  } else {
    return;
  }
  us h = f2bf(v);
  th[o] = h;
  tl[o] = f2bf(v - bf2f(h));
}

// C[M,N] = A[M,KAP] @ BT[N,KAP]^T from pre-split zero-K-padded planes.
// 64x64 tile, BK=64, 4 waves (2x2), wave = 2x2 16x16 frags.
// Register prefetch: gload(k+1) issued BEFORE comp(k); vmcnt waits land at
// sstore after compute, so HBM latency hides under MFMA + LDS reads.
// SPLIT: write Ch/Cl planes (row stride NPAD, zero-fill cols [N,NPAD)).
template <int KAP, bool BIAS, bool RELU, bool SPLIT>
__global__ __launch_bounds__(256) void gemm64_kernel(
    const us* __restrict__ Ah, const us* __restrict__ Al,
    const us* __restrict__ BTh, const us* __restrict__ BTl,
    const float* __restrict__ bias, float* __restrict__ Cf,
    us* __restrict__ Ch, us* __restrict__ Cl,
    int M, int N, int NPAD) {
  constexpr int BK = 64;
  constexpr int LDK = BK + 4;  // frag reads spread 2-way max (free)
  __shared__ us Ash[64][LDK];
  __shared__ us Asl[64][LDK];
  __shared__ us Bsh[64][LDK];
  __shared__ us Bsl[64][LDK];
  const int tid = threadIdx.x;
  const int lane = tid & 63;
  const int wid = tid >> 6;
  const int wm = wid >> 1, wn = wid & 1;  // 2x2 wave grid
  const int m0 = blockIdx.y * 64, n0 = blockIdx.x * 64;
  const int sr = tid >> 2, sko = (tid & 3) * 16;  // staging: row, k-offset
  const int arow = m0 + sr;
  const int brow = n0 + sr;
  const int l15 = lane & 15, kg = lane >> 4;
  const short8v zv = {0, 0, 0, 0, 0, 0, 0, 0};

  f32x4 acc[2][2];
#pragma unroll
  for (int i = 0; i < 2; ++i)
#pragma unroll
    for (int j = 0; j < 2; ++j)
#pragma unroll
      for (int c = 0; c < 4; ++c) acc[i][j][c] = 0.f;

  // prefetch registers (next K-step's tiles in flight)
  short8v pa0h, pa1h, pa0l, pa1l, pb0h, pb1h, pb0l, pb1l;
  auto gload = [&](int k0) {
    pa0h = pa1h = pa0l = pa1l = zv;
    pb0h = pb1h = pb0l = pb1l = zv;
    if (arow < M) {
      const size_t off = (size_t)arow * KAP + k0 + sko;
      pa0h = *reinterpret_cast<const short8v*>(Ah + off);
      pa1h = *reinterpret_cast<const short8v*>(Ah + off + 8);
      pa0l = *reinterpret_cast<const short8v*>(Al + off);
      pa1l = *reinterpret_cast<const short8v*>(Al + off + 8);
    }
    if (brow < N) {
      const size_t off = (size_t)brow * KAP + k0 + sko;
      pb0h = *reinterpret_cast<const short8v*>(BTh + off);
      pb1h = *reinterpret_cast<const short8v*>(BTh + off + 8);
      pb0l = *reinterpret_cast<const short8v*>(BTl + off);
      pb1l = *reinterpret_cast<const short8v*>(BTl + off + 8);
    }
  };
  auto sstore = [&]() {
    *reinterpret_cast<short8v*>(&Ash[sr][sko]) = pa0h;
    *reinterpret_cast<short8v*>(&Ash[sr][sko + 8]) = pa1h;
    *reinterpret_cast<short8v*>(&Asl[sr][sko]) = pa0l;
    *reinterpret_cast<short8v*>(&Asl[sr][sko + 8]) = pa1l;
    *reinterpret_cast<short8v*>(&Bsh[sr][sko]) = pb0h;
    *reinterpret_cast<short8v*>(&Bsh[sr][sko + 8]) = pb1h;
    *reinterpret_cast<short8v*>(&Bsl[sr][sko]) = pb0l;
    *reinterpret_cast<short8v*>(&Bsl[sr][sko + 8]) = pb1l;
  };

  gload(0);
  sstore();
  __syncthreads();
#pragma unroll
  for (int k0 = 0; k0 < KAP; k0 += BK) {
    const bool more = (k0 + BK < KAP);
    if (more) gload(k0 + BK);  // in flight under this step's compute
#pragma unroll
    for (int kc = 0; kc < BK; kc += 32) {
      short8v afh[2], afl[2], bfh[2], bfl[2];
#pragma unroll
      for (int mf = 0; mf < 2; ++mf) {
        const int r = wm * 32 + mf * 16 + l15;
        afh[mf] = *reinterpret_cast<const short8v*>(&Ash[r][kc + kg * 8]);
        afl[mf] = *reinterpret_cast<const short8v*>(&Asl[r][kc + kg * 8]);
      }
#pragma unroll
      for (int nf = 0; nf < 2; ++nf) {
        const int c = wn * 32 + nf * 16 + l15;
        bfh[nf] = *reinterpret_cast<const short8v*>(&Bsh[c][kc + kg * 8]);
        bfl[nf] = *reinterpret_cast<const short8v*>(&Bsl[c][kc + kg * 8]);
      }
#pragma unroll
      for (int mf = 0; mf < 2; ++mf)
#pragma unroll
        for (int nf = 0; nf < 2; ++nf) {
          acc[mf][nf] = __builtin_amdgcn_mfma_f32_16x16x32_bf16(afh[mf], bfh[nf], acc[mf][nf], 0, 0, 0);
          acc[mf][nf] = __builtin_amdgcn_mfma_f32_16x16x32_bf16(afh[mf], bfl[nf], acc[mf][nf], 0, 0, 0);
          acc[mf][nf] = __builtin_amdgcn_mfma_f32_16x16x32_bf16(afl[mf], bfh[nf], acc[mf][nf], 0, 0, 0);
        }
    }
    __syncthreads();  // all waves done reading LDS
    if (more) {
      sstore();  // vmcnt waits for prefetched regs land here, after compute
      __syncthreads();
    }
  }

  // epilogue: C/D layout col=lane&15, row=(lane>>4)*4+reg (guide §3, m89/m91)
#pragma unroll
  for (int nf = 0; nf < 2; ++nf) {
    const int col = n0 + wn * 32 + nf * 16 + l15;
    float bb = 0.f;
    if (BIAS && col < N) bb = bias[col];
#pragma unroll
    for (int mf = 0; mf < 2; ++mf) {
      const int rbase = m0 + wm * 32 + mf * 16 + kg * 4;
#pragma unroll
      for (int i = 0; i < 4; ++i) {
        const int row = rbase + i;
        if (row >= M) continue;
        if (col < N) {
          float v = acc[mf][nf][i];
          if (BIAS) v += bb;
          if (RELU) v = fmaxf(v, 0.f);
          if (SPLIT) {
            us h = f2bf(v);
            Ch[(size_t)row * NPAD + col] = h;
            Cl[(size_t)row * NPAD + col] = f2bf(v - bf2f(h));
          } else {
            Cf[(size_t)row * N + col] = v;
          }
        } else if (SPLIT && col < NPAD) {  // zero the K-pad for next GEMM
          Ch[(size_t)row * NPAD + col] = 0;
          Cl[(size_t)row * NPAD + col] = 0;
        }
      }
    }
  }
}

// Fused gather-aggregate + self-loop + bias + relu.
// NPW nodes/wave; F/4 lanes per node, ONE float4 per edge per lane.
// SPLIT: write bf16 hi/lo planes with row stride OST, zero-pad cols [F,OST).
template <int F, int OST, int NPW, bool SPLIT>
__global__ __launch_bounds__(256) void agg_gather_kernel(const int* __restrict__ rowptr,
                                                         const int* __restrict__ srcS,
                                                         const float* __restrict__ wS,
                                                         const float* __restrict__ t,
                                                         const float* __restrict__ dinv,
                                                         const float* __restrict__ bias,
                                                         float* __restrict__ out,
                                                         us* __restrict__ oh,
                                                         us* __restrict__ ol) {
  constexpr int LPN = F / 4;     // float4 lanes per node
  constexpr int LPNP = OST / 4;  // lanes incl. pad
  const int wv = threadIdx.x >> 6;
  const int lane = threadIdx.x & 63;
  const int sub = (NPW == 2) ? (lane >> 5) : 0;
  const int l = (NPW == 2) ? (lane & 31) : lane;
  const int node = blockIdx.x * (4 * NPW) + wv * NPW + sub;
  if (node >= NN) return;
  if (l >= LPN) {
    if (SPLIT && l < LPNP) {  // zero the K-pad for the next GEMM
      ushort4 z = make_ushort4(0, 0, 0, 0);
      *reinterpret_cast<ushort4*>(oh + (size_t)node * OST + l * 4) = z;
      *reinterpret_cast<ushort4*>(ol + (size_t)node * OST + l * 4) = z;
    }
    return;  // no barriers/shuffles below: safe exit
  }
  const int beg = rowptr[node], end = rowptr[node + 1];
  const size_t fo = (size_t)l * 4;
  float4 acc0 = make_float4(0.f, 0.f, 0.f, 0.f);
  float4 acc1 = make_float4(0.f, 0.f, 0.f, 0.f);
  int j = beg;
  for (; j + 1 < end; j += 2) {  // 2-way unroll: independent load->FMA chains
    const int s0 = srcS[j], s1 = srcS[j + 1];
    const float w0 = wS[j], w1 = wS[j + 1];
    const float4 v0 = *reinterpret_cast<const float4*>(t + (size_t)s0 * F + fo);
    const float4 v1 = *reinterpret_cast<const float4*>(t + (size_t)s1 * F + fo);
    acc0.x = fmaf(v0.x, w0, acc0.x); acc0.y = fmaf(v0.y, w0, acc0.y);
    acc0.z = fmaf(v0.z, w0, acc0.z); acc0.w = fmaf(v0.w, w0, acc0.w);
    acc1.x = fmaf(v1.x, w1, acc1.x); acc1.y = fmaf(v1.y, w1, acc1.y);
    acc1.z = fmaf(v1.z, w1, acc1.z); acc1.w = fmaf(v1.w, w1, acc1.w);
  }
  if (j < end) {
    const int s0 = srcS[j];
    const float w0 = wS[j];
    const float4 v0 = *reinterpret_cast<const float4*>(t + (size_t)s0 * F + fo);
    acc0.x = fmaf(v0.x, w0, acc0.x); acc0.y = fmaf(v0.y, w0, acc0.y);
    acc0.z = fmaf(v0.z, w0, acc0.z); acc0.w = fmaf(v0.w, w0, acc0.w);
  }
  const float di = dinv[node];
  const float sw = di * di;
  const float4 tv = *reinterpret_cast<const float4*>(t + (size_t)node * F + fo);
  const float4 bb = *reinterpret_cast<const float4*>(bias + fo);
  float4 o;
  o.x = fmaxf(fmaf(tv.x, sw, acc0.x + acc1.x) + bb.x, 0.f);
  o.y = fmaxf(fmaf(tv.y, sw, acc0.y + acc1.y) + bb.y, 0.f);
  o.z = fmaxf(fmaf(tv.z, sw, acc0.z + acc1.z) + bb.z, 0.f);
  o.w = fmaxf(fmaf(tv.w, sw, acc0.w + acc1.w) + bb.w, 0.f);
  if (SPLIT) {
    ushort4 hv, lv;
    hv.x = f2bf(o.x); lv.x = f2bf(o.x - bf2f(hv.x));
    hv.y = f2bf(o.y); lv.y = f2bf(o.y - bf2f(hv.y));
    hv.z = f2bf(o.z); lv.z = f2bf(o.z - bf2f(hv.z));
    hv.w = f2bf(o.w); lv.w = f2bf(o.w - bf2f(hv.w));
    *reinterpret_cast<ushort4*>(oh + (size_t)node * OST + fo) = hv;
    *reinterpret_cast<ushort4*>(ol + (size_t)node * OST + fo) = lv;
  } else {
    *reinterpret_cast<float4*>(out + (size_t)node * F + fo) = o;
  }
}

extern "C" void kernel_launch(void* const* d_in, const int* in_sizes, int n_in,
                              void* d_out, int out_size, void* d_ws, size_t ws_size,
                              hipStream_t stream) {
  const float* x = (const float*)d_in[0];
  const int* ei = (const int*)d_in[1];  // int32 per harness conversion
  const float* ea = (const float*)d_in[2];
  const float* fcW = (const float*)d_in[3];
  const float* fcb = (const float*)d_in[4];
  const float* W1 = (const float*)d_in[5];
  const float* b1 = (const float*)d_in[6];
  const float* W2 = (const float*)d_in[7];
  const float* b2 = (const float*)d_in[8];
  const int* srcIdx = ei;       // edge_index[0]
  const int* dstIdx = ei + NE;  // edge_index[1]

  char* ws = (char*)d_ws;
  constexpr size_t KB_ = 1u << 10;
  float* dinv = (float*)(ws);                    // 80000 B (doubles as deg)
  int* cnt = (int*)(ws + 80000);                 // 80000 B (count -> cursor)
  int* rowptr = (int*)(ws + 160000);             // 80004 B
  int* bsum = (int*)(ws + 244 * KB_);            // 320 B
  int* bpre = (int*)(ws + 245 * KB_);            // 320 B
  int* srcS = (int*)(ws + 256 * KB_);            // 1.28 MB
  float* wS = (float*)(ws + 1536 * KB_);         // 1.28 MB
  us* fcWTh = (us*)(ws + 2880 * KB_);            // 204800 B
  us* fcWTl = (us*)(ws + 3088 * KB_);
  us* W1Th = (us*)(ws + 3296 * KB_);             // 200x448x2 = 179200 B
  us* W1Tl = (us*)(ws + 3472 * KB_);
  us* W2Th = (us*)(ws + 3648 * KB_);             // 128x256x2 = 65536 B
  us* W2Tl = (us*)(ws + 3712 * KB_);             // ends exactly at 3776 KB
  us* xh = (us*)(ws + 3776 * KB_);               // 10.24 MB
  us* xl = (us*)(ws + 13784 * KB_);              // ends ~23.8 MB
  us* h1h = (us*)(ws + 23800 * KB_);             // 20000x448x2 = 17.92 MB
  us* h1l = (us*)(ws + 41350 * KB_);             // ends ~57.5 MB (peak)
  float* t1 = (float*)(ws + 3776 * KB_);         // 16 MB (x dead); also t2
  us* h2h = (us*)(ws + 23800 * KB_);             // 10.24 MB (h1 dead)
  us* h2l = (us*)(ws + 33800 * KB_);
  float* t2 = (float*)(ws + 3776 * KB_);         // 10.24 MB (t1 dead)

  // --- normalization + CSR (shared by both GCN layers) ---
  zero_kernel<<<(40000 / 4 + 255) / 256, 256, 0, stream>>>((float4*)ws, 40000 / 4);
  deg_count_kernel<<<(NE + NN + 255) / 256, 256, 0, stream>>>(dstIdx, ea, dinv, cnt);
  blocksum_dinv_kernel<<<SBLK, 256, 0, stream>>>(cnt, bsum, dinv);
  scanb_kernel<<<1, 128, 0, stream>>>(bsum, bpre);
  rowptr_kernel<<<SBLK, 256, 0, stream>>>(bpre, cnt, rowptr);
  scatter_kernel<<<(NE + 255) / 256, 256, 0, stream>>>(srcIdx, dstIdx, ea, dinv, cnt, srcS, wS);

  // --- one-time operand prep: split x + transpose/split all weights ---
  {
    constexpr int TOT = NN * IN_FT / 8 + HID1 * IN_FT + HID2 * K1P + OUT_FT * K2P;
    prep_kernel<<<(TOT + 255) / 256, 256, 0, stream>>>(
        x, xh, xl, fcW, W1, W2, fcWTh, fcWTl, W1Th, W1Tl, W2Th, W2Tl);
  }

  const int MBLK = (NN + 63) / 64;  // 313 row blocks

  // --- h1 = relu(x @ fcW + fcb), bf16 hi/lo planes [NN][448] ---
  gemm64_kernel<IN_FT, true, true, true><<<dim3((HID1 + 63) / 64, MBLK), 256, 0, stream>>>(
      xh, xl, fcWTh, fcWTl, fcb, nullptr, h1h, h1l, NN, HID1, K1P);

  // --- layer 1: t1 = h1 @ W1 (fp32); h2 = relu(agg(t1)+..) planes [NN][256] ---
  gemm64_kernel<K1P, false, false, false><<<dim3((HID2 + 63) / 64, MBLK), 256, 0, stream>>>(
      h1h, h1l, W1Th, W1Tl, nullptr, t1, nullptr, nullptr, NN, HID2, HID2);
  agg_gather_kernel<HID2, K2P, 1, true><<<(NN + 3) / 4, 256, 0, stream>>>(
      rowptr, srcS, wS, t1, dinv, b1, nullptr, h2h, h2l);

  // --- layer 2: t2 = h2 @ W2 (fp32); out = relu(agg(t2)+..) fp32 ---
  gemm64_kernel<K2P, false, false, false><<<dim3((OUT_FT + 63) / 64, MBLK), 256, 0, stream>>>(
      h2h, h2l, W2Th, W2Tl, nullptr, t2, nullptr, nullptr, NN, OUT_FT, OUT_FT);
  agg_gather_kernel<OUT_FT, OUT_FT, 2, false><<<(NN + 7) / 8, 256, 0, stream>>>(
      rowptr, srcS, wS, t2, dinv, b2, (float*)d_out, nullptr, nullptr);
}